// Round 16
// baseline (180.025 us; speedup 1.0000x reference)
//
#include <hip/hip_runtime.h>
#include <hip/hip_bf16.h>
#include <math.h>

#define SEQ 1024
#define BATCH 2
#define T 2048
#define DM 1024
#define NH 16
#define NOPE 32
#define HD 64
#define QL 20
#define KVL 20
#define KVA 52
#define HID 1024
#define NEXP 4
#define LSTR 80

typedef short bf16x8 __attribute__((ext_vector_type(8)));
typedef float f32x4 __attribute__((ext_vector_type(4)));
typedef float f32x16 __attribute__((ext_vector_type(16)));
typedef __hip_bfloat16 bf16;

static __device__ __forceinline__ float sigmoidf_(float x) {
    return 1.0f / (1.0f + __expf(-x));
}
static __device__ __forceinline__ unsigned short bfbits(float x) {
    bf16 h = __float2bfloat16(x);
    return *reinterpret_cast<unsigned short*>(&h);
}
static __device__ __forceinline__ unsigned cvt_pk_bf16(float lo, float hi) {
    unsigned r;
    asm("v_cvt_pk_bf16_f32 %0, %1, %2" : "=v"(r) : "v"(lo), "v"(hi));
    return r;
}
static __device__ __forceinline__ void gload16(const bf16* g, char* l) {
    __builtin_amdgcn_global_load_lds(
        (const __attribute__((address_space(1))) unsigned int*)g,
        (__attribute__((address_space(3))) unsigned int*)l, 16, 0, 0);
}
static __device__ __forceinline__ void barrier_() {
    asm volatile("" ::: "memory");
    __builtin_amdgcn_s_barrier();
    asm volatile("" ::: "memory");
}
#define VMWAIT(N) asm volatile("s_waitcnt vmcnt(" #N ")" ::: "memory")

// ---------------------------------------------------------------------------
// k_setup: all weight preprocessing in one launch.
// ---------------------------------------------------------------------------
__global__ __launch_bounds__(256) void k_setup(
    const float* __restrict__ wo, const float* __restrict__ sg,
    const float* __restrict__ su, const float* __restrict__ sd,
    const float* __restrict__ eg, const float* __restrict__ eu,
    const float* __restrict__ ed,
    bf16* __restrict__ woT, bf16* __restrict__ sgT, bf16* __restrict__ suT,
    bf16* __restrict__ sdT, bf16* __restrict__ egT, bf16* __restrict__ euT,
    bf16* __restrict__ edT,
    const float* __restrict__ wq_a, const float* __restrict__ wkv_a,
    const float* __restrict__ wq_b, const float* __restrict__ wkv_b,
    bf16* __restrict__ loraT, bf16* __restrict__ wqbT, bf16* __restrict__ wkvbT,
    float* __restrict__ ctab, float* __restrict__ stab)
{
    int z = blockIdx.z;
    int tid = threadIdx.x;
    if (z < 16) {
        __shared__ float tile[32][33];
        const float* in; bf16* out;
        if      (z == 0) { in = wo; out = woT; }
        else if (z == 1) { in = sg; out = sgT; }
        else if (z == 2) { in = su; out = suT; }
        else if (z == 3) { in = sd; out = sdT; }
        else if (z < 8)  { size_t o = (size_t)(z - 4)  * DM * HID; in = eg + o; out = egT + o; }
        else if (z < 12) { size_t o = (size_t)(z - 8)  * DM * HID; in = eu + o; out = euT + o; }
        else             { size_t o = (size_t)(z - 12) * HID * DM; in = ed + o; out = edT + o; }
        int c0 = blockIdx.x * 32, r0 = blockIdx.y * 32;
        int tx = tid & 31, ty = tid >> 5;
        #pragma unroll
        for (int ii = 0; ii < 4; ++ii)
            tile[ty + ii * 8][tx] = in[(size_t)(r0 + ty + ii * 8) * 1024 + c0 + tx];
        __syncthreads();
        int c = tid >> 3, rg = (tid & 7) * 4;
        ushort4 o4;
        o4.x = bfbits(tile[rg + 0][c]);
        o4.y = bfbits(tile[rg + 1][c]);
        o4.z = bfbits(tile[rg + 2][c]);
        o4.w = bfbits(tile[rg + 3][c]);
        *(ushort4*)&out[(size_t)(c0 + c) * 1024 + r0 + rg] = o4;
    } else if (z == 16) {
        int s = blockIdx.y * 32 + blockIdx.x;
        int p = tid;
        float freq = exp2f(-(float)p * (13.287712379549449f / 256.0f));
        float ang = (float)s * freq;
        float sn, cs;
        __sincosf(ang, &sn, &cs);
        ctab[s * 256 + p] = cs;
        stab[s * 256 + p] = sn;
    } else {
        int idx = (blockIdx.y * 32 + blockIdx.x) * 256 + tid;
        if (z == 17) {
            if (idx >= 80 * 1024) return;
            int n = idx >> 10, k = idx & 1023;
            float v = (n < 20) ? wq_a[k * QL + n] : (n < 72 ? wkv_a[k * KVA + (n - 20)] : 0.f);
            loraT[idx] = __float2bfloat16(v);
        } else if (z == 18) {
            if (idx >= 1024 * 32) return;
            int n = idx >> 5, k = idx & 31;
            wqbT[idx] = __float2bfloat16(k < 20 ? wq_b[k * DM + n] : 0.f);
        } else {
            if (idx >= 1536 * 32) return;
            int n = idx >> 5, k = idx & 31;
            wkvbT[idx] = __float2bfloat16(k < 20 ? wkv_b[k * (NH * 96) + n] : 0.f);
        }
    }
}

// ---------------------------------------------------------------------------
// k_p1: lora partials = dec @ [wq_a|wkv_a] via MFMA, kz in {0,1}.
// ---------------------------------------------------------------------------
__global__ __launch_bounds__(256) void k_p1(
    const float* __restrict__ dec, const bf16* __restrict__ loraT,
    float* __restrict__ lora4)
{
    __shared__ __align__(16) char As[128 * LSTR];
    __shared__ __align__(16) char Bs[80 * LSTR];
    const int tid = threadIdx.x;
    const int kz = blockIdx.x;
    const int m0 = blockIdx.y * 128;
    const int lane = tid & 63, wave = tid >> 6;
    const int g = lane >> 4, c = lane & 15;
    f32x4 acc[2][5] = {};
    for (int ks = 0; ks < 16; ++ks) {
        int k0 = kz * 512 + ks * 32;
        __syncthreads();
        #pragma unroll
        for (int pass = 0; pass < 4; ++pass) {
            int row = (tid >> 3) + pass * 32;
            int t = m0 + row;
            int b = t >> 10, s = t & 1023;
            f32x4 v = *(const f32x4*)&dec[(size_t)(s * 2 + b) * DM + k0 + (tid & 7) * 4];
            ushort4 h4;
            h4.x = bfbits(v[0]); h4.y = bfbits(v[1]);
            h4.z = bfbits(v[2]); h4.w = bfbits(v[3]);
            *(ushort4*)&As[row * LSTR + (tid & 7) * 8] = h4;
        }
        if (tid < 160) {
            int row = tid >> 1, hf = tid & 1;
            const bf16* src = &loraT[row * 1024 + k0 + hf * 16];
            *(int4*)&Bs[row * LSTR + hf * 32]      = *(const int4*)&src[0];
            *(int4*)&Bs[row * LSTR + hf * 32 + 16] = *(const int4*)&src[8];
        }
        __syncthreads();
        bf16x8 af[2], bff[5];
        #pragma unroll
        for (int mi = 0; mi < 2; ++mi)
            af[mi] = *(const bf16x8*)&As[(wave * 32 + mi * 16 + c) * LSTR + 16 * g];
        #pragma unroll
        for (int nf = 0; nf < 5; ++nf)
            bff[nf] = *(const bf16x8*)&Bs[(nf * 16 + c) * LSTR + 16 * g];
        #pragma unroll
        for (int mi = 0; mi < 2; ++mi)
            #pragma unroll
            for (int nf = 0; nf < 5; ++nf)
                acc[mi][nf] = __builtin_amdgcn_mfma_f32_16x16x32_bf16(af[mi], bff[nf], acc[mi][nf], 0, 0, 0);
    }
    #pragma unroll
    for (int mi = 0; mi < 2; ++mi)
        #pragma unroll
        for (int nf = 0; nf < 5; ++nf)
            #pragma unroll
            for (int r = 0; r < 4; ++r) {
                int col = nf * 16 + c;
                if (col < 72) {
                    int row = m0 + wave * 32 + mi * 16 + 4 * g + r;
                    lora4[((size_t)kz * T + row) * 72 + col] = acc[mi][nf][r];
                }
            }
}

// ---------------------------------------------------------------------------
// k_p2m: merged RMS (blocks 0..7) + k_pe RoPE (all T blocks).
// ---------------------------------------------------------------------------
__global__ __launch_bounds__(256) void k_p2m(
    const float* __restrict__ lora4, const float* __restrict__ qnw,
    const float* __restrict__ kvnw, const float* __restrict__ ctab,
    const float* __restrict__ stab, bf16* __restrict__ nrmq,
    bf16* __restrict__ nrmkv, bf16* __restrict__ kb, int* __restrict__ cnt)
{
    int bid = blockIdx.x, tid = threadIdx.x;
    if (bid == 0 && tid < 16) cnt[tid] = 0;
    {
        int t = bid, p = tid;
        int r = p & 15, h = p >> 4, s = t & (SEQ - 1);
        float y0 = lora4[t * 72 + 40 + 2 * r] + lora4[(size_t)(T + t) * 72 + 40 + 2 * r];
        float y1 = lora4[t * 72 + 41 + 2 * r] + lora4[(size_t)(T + t) * 72 + 41 + 2 * r];
        float cs = ctab[s * 256 + p], sn = stab[s * 256 + p];
        ushort2 pk;
        pk.x = bfbits(y0 * cs - y1 * sn);
        pk.y = bfbits(y0 * sn + y1 * cs);
        *(ushort2*)&kb[(size_t)t * DM + h * HD + NOPE + 2 * r] = pk;
    }
    if (bid < 8) {
        int t = bid * 256 + tid;
        float lq[20], lk[20];
        float ssq = 0.f, ssk = 0.f;
        #pragma unroll
        for (int i = 0; i < 20; ++i) {
            lq[i] = lora4[t * 72 + i] + lora4[(size_t)(T + t) * 72 + i];
            ssq += lq[i] * lq[i];
        }
        #pragma unroll
        for (int i = 0; i < 20; ++i) {
            lk[i] = lora4[t * 72 + 20 + i] + lora4[(size_t)(T + t) * 72 + 20 + i];
            ssk += lk[i] * lk[i];
        }
        float fq = rsqrtf(ssq / 20.f + 1e-6f);
        float fk = rsqrtf(ssk / 20.f + 1e-6f);
        #pragma unroll
        for (int i = 0; i < 32; ++i) {
            nrmq[t * 32 + i]  = __float2bfloat16(i < 20 ? lq[i] * fq * qnw[i]  : 0.f);
            nrmkv[t * 32 + i] = __float2bfloat16(i < 20 ? lk[i] * fk * kvnw[i] : 0.f);
        }
    }
}

// ---------------------------------------------------------------------------
// k_p3: merged q-expand (z=0) and kv-expand (z=1).
// ---------------------------------------------------------------------------
__global__ __launch_bounds__(256) void k_p3(
    const bf16* __restrict__ nrmq, const bf16* __restrict__ wqbT,
    const bf16* __restrict__ nrmkv, const bf16* __restrict__ wkvbT,
    const float* __restrict__ ctab, const float* __restrict__ stab,
    bf16* __restrict__ qb, bf16* __restrict__ kb, bf16* __restrict__ vt_g)
{
    const int zq = (blockIdx.z == 0);
    if (zq && blockIdx.x >= 16) return;
    __shared__ __align__(16) char As[128 * LSTR];
    __shared__ __align__(16) char Bs[64 * LSTR];
    const int tid = threadIdx.x;
    const int m0 = blockIdx.y * 128, n0 = blockIdx.x * 64;
    const int lane = tid & 63, wave = tid >> 6;
    const int g = lane >> 4, c = lane & 15;
    const int wm = wave >> 1, wn = wave & 1;
    const bf16* nrm = zq ? nrmq : nrmkv;
    const bf16* wT  = zq ? wqbT : wkvbT;
    {
        int row = tid >> 1, hf = tid & 1;
        const bf16* sa = &nrm[(size_t)(m0 + row) * 32 + hf * 16];
        *(int4*)&As[row * LSTR + hf * 32]      = *(const int4*)&sa[0];
        *(int4*)&As[row * LSTR + hf * 32 + 16] = *(const int4*)&sa[8];
        int brow = tid >> 2;
        *(int4*)&Bs[brow * LSTR + (tid & 3) * 16] = *(const int4*)&wT[(size_t)(n0 + brow) * 32 + (tid & 3) * 8];
    }
    __syncthreads();
    f32x4 acc[4][2] = {};
    bf16x8 af[4], bfr[2];
    #pragma unroll
    for (int mi = 0; mi < 4; ++mi)
        af[mi] = *(const bf16x8*)&As[(wm * 64 + mi * 16 + c) * LSTR + 16 * g];
    #pragma unroll
    for (int ni = 0; ni < 2; ++ni)
        bfr[ni] = *(const bf16x8*)&Bs[(wn * 32 + ni * 16 + c) * LSTR + 16 * g];
    #pragma unroll
    for (int mi = 0; mi < 4; ++mi)
        #pragma unroll
        for (int ni = 0; ni < 2; ++ni)
            acc[mi][ni] = __builtin_amdgcn_mfma_f32_16x16x32_bf16(af[mi], bfr[ni], acc[mi][ni], 0, 0, 0);

    if (zq) {
        #pragma unroll
        for (int mi = 0; mi < 4; ++mi)
            #pragma unroll
            for (int ni = 0; ni < 2; ++ni) {
                #pragma unroll
                for (int r = 0; r < 4; ++r) acc[mi][ni][r] *= 0.18033688f;  // 0.125*log2(e)
                int n = n0 + wn * 32 + ni * 16 + c;
                int w = n & 63;
                if (w < 32) {
                    #pragma unroll
                    for (int r = 0; r < 4; ++r) {
                        int row = m0 + wm * 64 + mi * 16 + 4 * g + r;
                        qb[(size_t)row * DM + n] = __float2bfloat16(acc[mi][ni][r]);
                    }
                } else {
                    int h = n >> 6;
                    int pidx = h * 16 + ((w - 32) >> 1);
                    int odd = w & 1;
                    #pragma unroll
                    for (int r = 0; r < 4; ++r) {
                        int row = m0 + wm * 64 + mi * 16 + 4 * g + r;
                        int s = row & (SEQ - 1);
                        float own = acc[mi][ni][r];
                        float oth = __shfl_xor(own, 1);
                        float cs = ctab[s * 256 + pidx], sn = stab[s * 256 + pidx];
                        float o = odd ? (oth * sn + own * cs) : (own * cs - oth * sn);
                        qb[(size_t)row * DM + n] = __float2bfloat16(o);
                    }
                }
            }
    } else {
        #pragma unroll
        for (int mi = 0; mi < 4; ++mi)
            #pragma unroll
            for (int ni = 0; ni < 2; ++ni) {
                int n = n0 + wn * 32 + ni * 16 + c;
                int h = n / 96, w = n - h * 96;
                int row0 = m0 + wm * 64 + mi * 16 + 4 * g;
                if (w < NOPE) {
                    #pragma unroll
                    for (int r = 0; r < 4; ++r)
                        kb[(size_t)(row0 + r) * DM + h * HD + w] = __float2bfloat16(acc[mi][ni][r]);
                } else {
                    int d = w - NOPE;
                    int b = row0 >> 10, s0 = row0 & (SEQ - 1);
                    ushort4 v4;
                    v4.x = bfbits(acc[mi][ni][0]);
                    v4.y = bfbits(acc[mi][ni][1]);
                    v4.z = bfbits(acc[mi][ni][2]);
                    v4.w = bfbits(acc[mi][ni][3]);
                    *(ushort4*)&vt_g[(((size_t)(b * NH + h) * HD + d) << 10) + s0] = v4;
                }
            }
    }
}

// ---------------------------------------------------------------------------
// k_attn: champion version (4 waves, 64 q rows, gload staging, LDS overlay).
// ---------------------------------------------------------------------------
__global__ __launch_bounds__(256) void k_attn(
    const bf16* __restrict__ qb, const bf16* __restrict__ kb,
    const bf16* __restrict__ vt_g, bf16* __restrict__ ab)
{
    __shared__ __align__(16) char stage[2][16384];

    const int orig = blockIdx.y * 8 + blockIdx.x;
    const int h  = (orig & 7) * 2 + ((orig >> 3) & 1);
    const int qt = orig >> 4;
    const int b = blockIdx.z;
    const int tid = threadIdx.x;
    const int lane = tid & 63, wave = tid >> 6;
    const int l31 = lane & 31, hi = lane >> 5;
    const int sp = wave >> 1, wq = wave & 1;
    const int q0 = qt * 64 + wq * 32;
    char* ks = stage[sp];
    char* vt = stage[sp] + 8192;

    const int scol = ((lane & 7) * 8) ^ ((lane >> 3) << 3);
    const int srowL = lane >> 3;

    bf16x8 qf[4];
    {
        const bf16* qrow = &qb[(size_t)(b * SEQ + q0 + l31) * DM + h * HD + 8 * hi];
        #pragma unroll
        for (int st = 0; st < 4; ++st)
            qf[st] = *(const bf16x8*)&qrow[16 * st];
    }

    f32x16 o0 = {}, o1 = {};
    float m_run = -3.0e38f, l_run = 0.f;
    const size_t vbase = ((size_t)(b * NH + h) * HD) << 10;

    for (int ktl = 0; ktl < 8; ++ktl) {
        const int kt = sp * 8 + ktl;
        __syncthreads();
        #pragma unroll
        for (int ps = 0; ps < 4; ++ps) {
            int rbase = ps * 16 + wq * 8;
            int row = rbase + srowL;
            gload16(&kb[(size_t)(b * SEQ + kt * 64 + row) * DM + h * HD + scol],
                    ks + rbase * 128);
            gload16(&vt_g[vbase + ((size_t)row << 10) + kt * 64 + scol],
                    vt + rbase * 128);
        }
        VMWAIT(0);
        __syncthreads();

        f32x16 sc0 = {}, sc1 = {};
        __builtin_amdgcn_s_setprio(1);
        #pragma unroll
        for (int st = 0; st < 4; ++st) {
            int colb = 32 * st + 16 * hi;
            int r0 = l31;
            bf16x8 kf0 = *(const bf16x8*)&ks[r0 * 128 + (colb ^ ((r0 & 7) << 4))];
            sc0 = __builtin_amdgcn_mfma_f32_32x32x16_bf16(kf0, qf[st], sc0, 0, 0, 0);
            int r1 = 32 + l31;
            bf16x8 kf1 = *(const bf16x8*)&ks[r1 * 128 + (colb ^ ((r1 & 7) << 4))];
            sc1 = __builtin_amdgcn_mfma_f32_32x32x16_bf16(kf1, qf[st], sc1, 0, 0, 0);
        }
        __builtin_amdgcn_s_setprio(0);

        float mt = fmaxf(sc0[0], sc1[0]);
        #pragma unroll
        for (int i = 1; i < 16; ++i) mt = fmaxf(mt, fmaxf(sc0[i], sc1[i]));
        mt = fmaxf(mt, __shfl_xor(mt, 32));

        if (!__all(mt <= m_run + 8.0f)) {
            float m_new = fmaxf(m_run, mt);
            float corr = exp2f(m_run - m_new);
            m_run = m_new;
            l_run *= corr;
            #pragma unroll
            for (int i = 0; i < 16; ++i) { o0[i] *= corr; o1[i] *= corr; }
        }
        float ls = 0.f;
        #pragma unroll
        for (int i = 0; i < 16; ++i) {
            sc0[i] = exp2f(sc0[i] - m_run);
            sc1[i] = exp2f(sc1[i] - m_run);
            ls += sc0[i] + sc1[i];
        }
        ls += __shfl_xor(ls, 32);
        l_run += ls;

        unsigned pk0[8], pk1[8];
        #pragma unroll
        for (int i = 0; i < 8; ++i) {
            pk0[i] = cvt_pk_bf16(sc0[2 * i], sc0[2 * i + 1]);
            pk1[i] = cvt_pk_bf16(sc1[2 * i], sc1[2 * i + 1]);
        }

        __builtin_amdgcn_s_setprio(1);
#define PV_SUB(PK, KK)                                                          \
        {                                                                       \
            _Pragma("unroll")                                                   \
            for (int s = 0; s < 2; ++s) {                                       \
                unsigned sx = hi ? PK[4*s]   : PK[4*s+2];                       \
                unsigned rx = __shfl_xor(sx, 32);                               \
                unsigned sy = hi ? PK[4*s+1] : PK[4*s+3];                       \
                unsigned ry = __shfl_xor(sy, 32);                               \
                int4 bi;                                                        \
                bi.x = hi ? (int)rx : (int)PK[4*s];                             \
                bi.y = hi ? (int)ry : (int)PK[4*s+1];                           \
                bi.z = hi ? (int)PK[4*s+2] : (int)rx;                           \
                bi.w = hi ? (int)PK[4*s+3] : (int)ry;                           \
                bf16x8 bfr = *(bf16x8*)&bi;                                     \
                int cb = (KK) * 64 + 32 * s + 16 * hi;                          \
                {                                                               \
                    int vr = l31;                                               \
                    bf16x8 vf = *(const bf16x8*)&vt[vr * 128 + (cb ^ ((vr & 7) << 4))]; \
                    o0 = __builtin_amdgcn_mfma_f32_32x32x16_bf16(vf, bfr, o0, 0, 0, 0); \
                }                                                               \
                {                                                               \
                    int vr = 32 + l31;                                          \
                    bf16x8 vf = *(const bf16x8*)&vt[vr * 128 + (cb ^ ((vr & 7) << 4))]; \
                    o1 = __builtin_amdgcn_mfma_f32_32x32x16_bf16(vf, bfr, o1, 0, 0, 0); \
                }                                                               \
            }                                                                   \
        }
        PV_SUB(pk0, 0)
        PV_SUB(pk1, 1)
#undef PV_SUB
        __builtin_amdgcn_s_setprio(0);
    }

    float* polB = (float*)stage[0];
    float* mllB = (float*)(stage[0] + 16640);

    __syncthreads();
    if (sp == 1) {
        #pragma unroll
        for (int i = 0; i < 16; ++i) {
            int d = (i & 3) + 8 * (i >> 2) + 4 * hi;
            polB[(wq * 32 + l31) * 65 + d]      = o0[i];
            polB[(wq * 32 + l31) * 65 + 32 + d] = o1[i];
        }
        if (hi == 0) {
            mllB[(wq * 32 + l31) * 2 + 0] = m_run;
            mllB[(wq * 32 + l31) * 2 + 1] = l_run;
        }
    }
    __syncthreads();
    if (sp == 0) {
        float m_b = mllB[(wq * 32 + l31) * 2 + 0];
        float l_b = mllB[(wq * 32 + l31) * 2 + 1];
        float M = fmaxf(m_run, m_b);
        float wa = exp2f(m_run - M), wb = exp2f(m_b - M);
        float inv = 1.0f / (l_run * wa + l_b * wb);
        #pragma unroll
        for (int i = 0; i < 16; ++i) {
            int d = (i & 3) + 8 * (i >> 2) + 4 * hi;
            o0[i] = (o0[i] * wa + polB[(wq * 32 + l31) * 65 + d]      * wb) * inv;
            o1[i] = (o1[i] * wa + polB[(wq * 32 + l31) * 65 + 32 + d] * wb) * inv;
        }
    }
    __syncthreads();
    if (sp == 0) {
        char* tb = stage[1] + (wq ? 8192 : 1024);
        #pragma unroll
        for (int i = 0; i < 8; ++i) {
            int dbase = 2 * (i & 1) + 8 * (i >> 1) + 4 * hi;
            *(unsigned*)&tb[l31 * 140 + (dbase) * 2]      = cvt_pk_bf16(o0[2 * i], o0[2 * i + 1]);
            *(unsigned*)&tb[l31 * 140 + (32 + dbase) * 2] = cvt_pk_bf16(o1[2 * i], o1[2 * i + 1]);
        }
        __builtin_amdgcn_s_waitcnt(0);
        #pragma unroll
        for (int p = 0; p < 8; ++p) {
            int idx = p * 64 + lane;
            int q = idx >> 4, c8 = idx & 15;
            int2 rv;
            rv.x = *(const int*)&tb[q * 140 + c8 * 8];
            rv.y = *(const int*)&tb[q * 140 + c8 * 8 + 4];
            *(int2*)&ab[(size_t)(b * SEQ + q0 + q) * DM + h * HD + c8 * 4] = rv;
        }
    }
}

// ---------------------------------------------------------------------------
// k_mm_plain: champion version (tri-buffered, 1 barrier/K-step, XCD swizzle).
// ---------------------------------------------------------------------------
__global__ __launch_bounds__(512) void k_mm_plain(
    const bf16* __restrict__ A, const bf16* __restrict__ Bt, bf16* __restrict__ C)
{
    __shared__ __align__(16) char As[3][8192];
    __shared__ __align__(16) char Bs[3][4096];
    const int tid = threadIdx.x;
    const int lane = tid & 63, wave = tid >> 6;
    const int g = lane >> 4, c = lane & 15;
    const int wm = wave >> 1, wn = wave & 1;
    int orig = blockIdx.y * 16 + blockIdx.x;
    int swz = (orig & 7) * 32 + (orig >> 3);
    const int n0 = (swz & 15) * 64, m0 = (swz >> 4) * 128;

    const int ldr = lane >> 2;
    const int ldc = (lane & 3) * 8;
    const bf16* agp = &A[(size_t)(m0 + wave * 16 + ldr) * DM + ldc];
    const bool doB = wave >= 4;
    const bf16* bgp = &Bt[(size_t)(n0 + (wave & 3) * 16 + ldr) * DM + ldc];
    const int aoffL = wave * 1024, boffL = (wave & 3) * 1024;

    f32x4 acc[2][2] = {};
    const int NT = DM / 32;
    gload16(agp, As[0] + aoffL);
    if (doB) gload16(bgp, Bs[0] + boffL);
    int cur = 0;
    for (int k = 0; k < NT; ++k) {
        if (k + 1 < NT) {
            int nxt = (cur + 1) % 3;
            gload16(agp + (k + 1) * 32, As[nxt] + aoffL);
            if (doB) gload16(bgp + (k + 1) * 32, Bs[nxt] + boffL);
            if (doB) VMWAIT(2); else VMWAIT(1);
        } else {
            VMWAIT(0);
        }
        barrier_();
        bf16x8 af[2], bfx[2];
        #pragma unroll
        for (int mi = 0; mi < 2; ++mi)
            af[mi] = *(const bf16x8*)&As[cur][(wm * 32 + mi * 16 + c) * 64 + g * 16];
        #pragma unroll
        for (int ni = 0; ni < 2; ++ni)
            bfx[ni] = *(const bf16x8*)&Bs[cur][(wn * 32 + ni * 16 + c) * 64 + g * 16];
        #pragma unroll
        for (int mi = 0; mi < 2; ++mi)
            #pragma unroll
            for (int ni = 0; ni < 2; ++ni)
                acc[mi][ni] = __builtin_amdgcn_mfma_f32_16x16x32_bf16(af[mi], bfx[ni], acc[mi][ni], 0, 0, 0);
        cur = (cur + 1) % 3;
    }
    #pragma unroll
    for (int mi = 0; mi < 2; ++mi)
        #pragma unroll
        for (int ni = 0; ni < 2; ++ni)
            #pragma unroll
            for (int r = 0; r < 4; ++r)
                C[(size_t)(m0 + wm * 32 + mi * 16 + 4 * g + r) * DM + n0 + wn * 32 + ni * 16 + c]
                    = __float2bfloat16(acc[mi][ni][r]);
}

// ---------------------------------------------------------------------------
// k_mm_gu_all v5: BM=128 x BN=128 block, 8 waves (2 wm x 4 wn), wave tile
// 64x32, dual-B. Each wave stages 16 rows of A + Bg + Bu (3 gloads, 1KB
// each). Tri-buffered (72KB LDS -> 2 blocks/CU), counted vmcnt(3),
// one barrier per K-step. Same 64B conflict-free rows. XCD swizzle over
// 128 xy-blocks.
// ---------------------------------------------------------------------------
__global__ __launch_bounds__(512) void k_mm_gu_all(
    const bf16* __restrict__ X, const bf16* __restrict__ egT,
    const bf16* __restrict__ euT, const bf16* __restrict__ sgT,
    const bf16* __restrict__ suT, const int* __restrict__ cnt,
    const int* __restrict__ lists, bf16* __restrict__ act_r,
    bf16* __restrict__ act_s)
{
    const int e = blockIdx.z;
    const bool SH = (e == 4);
    const int ntok = SH ? T : cnt[e];
    int orig = blockIdx.y * 8 + blockIdx.x;            // 128 xy-blocks
    int swz = (orig & 7) * 16 + (orig >> 3);           // bijective (128%8==0)
    const int n0 = (swz & 7) * 128, m0 = (swz >> 3) * 128;
    if (m0 >= ntok) return;
    __shared__ __align__(16) char As[3][8192];
    __shared__ __align__(16) char Bg[3][8192];
    __shared__ __align__(16) char Bu[3][8192];
    __shared__ int rowid[128];
    const int tid = threadIdx.x;
    if (tid < 128) {
        int idx = m0 + tid;
        rowid[tid] = SH ? idx : lists[e * T + (idx < ntok ? idx : ntok - 1)];
    }
    __syncthreads();
    const int lane = tid & 63, wave = tid >> 6;
    const int g = lane >> 4, c = lane & 15;
    const int wm = wave >> 2, wn = wave & 3;           // 2 x 4 wave grid
    const bf16* Bge = SH ? sgT : egT + (size_t)e * HID * DM;
    const bf16* Bue = SH ? suT : euT + (size_t)e * HID * DM;
    bf16* act = SH ? act_s : act_r;

    const int ldr = lane >> 2;
    const int ldc = (lane & 3) * 8;
    const int myTok = rowid[wave * 16 + ldr];
    const bf16* agp  = &X[(size_t)myTok * DM + ldc];
    const bf16* bgpg = &Bge[(size_t)(n0 + wave * 16 + ldr) * DM + ldc];
    const bf16* bgpu = &Bue[(size_t)(n0 + wave * 16 + ldr) * DM + ldc];
    const int offL = wave * 1024;

    f32x4 accg[4][2] = {}, accu[4][2] = {};
    const int NT = DM / 32;
    gload16(agp,  As[0] + offL);
    gload16(bgpg, Bg[0] + offL);
    gload16(bgpu, Bu[0] + offL);
    int cur = 0;
    for (int k = 0; k < NT; ++k) {
        if (k + 1 < NT) {
            int nxt = (cur + 1) % 3;
            gload16(agp  + (k + 1) * 32, As[nxt] + offL);
            gload16(bgpg + (k + 1) * 32, Bg[nxt] + offL);
            gload16(bgpu + (k + 1) * 32, Bu[nxt] + offL);
            VMWAIT(3);
        } else {
            VMWAIT(0);
        }
        barrier_();
        bf16x8 af[4], gf[2], uf[2];
        #pragma unroll
        for (int mi = 0; mi < 4; ++mi)
            af[mi] = *(const bf16x8*)&As[cur][(wm * 64 + mi * 16 + c) * 64 + g * 16];
        #pragma unroll
        for (int ni = 0; ni < 2; ++ni) {
            gf[ni] = *(const bf16x8*)&Bg[cur][(wn * 32 + ni * 16 + c) * 64 + g * 16];
            uf[ni] = *(const bf16x8*)&Bu[cur][(wn * 32 + ni * 16 + c) * 64 + g * 16];
        }
        #pragma unroll
        for (int mi = 0; mi < 4; ++mi)
            #pragma unroll
            for (int ni = 0; ni < 2; ++ni) {
                accg[mi][ni] = __builtin_amdgcn_mfma_f32_16x16x32_bf16(af[mi], gf[ni], accg[mi][ni], 0, 0, 0);
                accu[mi][ni] = __builtin_amdgcn_mfma_f32_16x16x32_bf16(af[mi], uf[ni], accu[mi][ni], 0, 0, 0);
            }
        cur = (cur + 1) % 3;
    }
    #pragma unroll
    for (int mi = 0; mi < 4; ++mi)
        #pragma unroll
        for (int ni = 0; ni < 2; ++ni)
            #pragma unroll
            for (int r = 0; r < 4; ++r) {
                int lr = wm * 64 + mi * 16 + 4 * g + r;
                if (!SH && m0 + lr >= ntok) continue;
                int token = rowid[lr];
                float gv = accg[mi][ni][r], uv = accu[mi][ni][r];
                act[(size_t)token * HID + n0 + wn * 32 + ni * 16 + c] =
                    __float2bfloat16(gv * sigmoidf_(gv) * uv);
            }
}

// fused down: out = (act_r @ exp_down[e]) * wtok + (act_s @ sh_down), tri-buffered
__global__ __launch_bounds__(512) void k_mm_down_f(
    const bf16* __restrict__ Xr, const bf16* __restrict__ Xs,
    const bf16* __restrict__ edT, const bf16* __restrict__ sdT,
    const int* __restrict__ cnt, const int* __restrict__ lists,
    const float* __restrict__ wtok, float* __restrict__ out)
{
    const int e = blockIdx.z;
    const int ntok = cnt[e];
    int orig = blockIdx.y * 16 + blockIdx.x;
    int swz = (orig & 7) * 32 + (orig >> 3);
    const int n0 = (swz & 15) * 64, m0 = (swz >> 4) * 128;
    if (m0 >= ntok) return;
    __shared__ __align__(16) char Ar[3][8192];
    __shared__ __align__(16) char Az[3][8192];
    __shared__ __align__(16) char Br[3][4096];
    __shared__ __align__(16) char Bz[3][4096];
    __shared__ int rowid[128];
    const int tid = threadIdx.x;
    if (tid < 128) {
        int idx = m0 + tid;
        rowid[tid] = lists[e * T + (idx < ntok ? idx : ntok - 1)];
    }
    __syncthreads();
    const int lane = tid & 63, wave = tid >> 6;
    const int g = lane >> 4, c = lane & 15;
    const int wm = wave >> 1, wn = wave & 1;
    const bf16* Bde = edT + (size_t)e * HID * DM;

    const int ldr = lane >> 2;
    const int ldc = (lane & 3) * 8;
    const int myTok = rowid[wave * 16 + ldr];
    const bf16* agr = &Xr[(size_t)myTok * HID + ldc];
    const bf16* ags = &Xs[(size_t)myTok * HID + ldc];
    const bool isR = wave < 4;
    const bf16* bgp = (isR ? Bde : sdT) + (size_t)(n0 + (wave & 3) * 16 + ldr) * HID + ldc;
    const int aoffL = wave * 1024, boffL = (wave & 3) * 1024;

    f32x4 accr[2][2] = {}, accs[2][2] = {};
    const int NT = HID / 32;
    gload16(agr, Ar[0] + aoffL);
    gload16(ags, Az[0] + aoffL);
    gload16(bgp, (isR ? Br[0] : Bz[0]) + boffL);
    int cur = 0;
    for (int k = 0; k < NT; ++k) {
        if (k + 1 < NT) {
            int nxt = (cur + 1) % 3;
            gload16(agr + (k + 1) * 32, Ar[nxt] + aoffL);
            gload16(ags + (k + 1) * 32, Az[nxt] + aoffL);
            gload16(bgp + (k + 1) * 32, (isR ? Br[nxt] : Bz[nxt]) + boffL);
            VMWAIT(3);
        } else {
            VMWAIT(0);
        }
        barrier_();
        bf16x8 afr[2], afs[2], bfr[2], bfs[2];
        #pragma unroll
        for (int mi = 0; mi < 2; ++mi) {
            afr[mi] = *(const bf16x8*)&Ar[cur][(wm * 32 + mi * 16 + c) * 64 + g * 16];
            afs[mi] = *(const bf16x8*)&Az[cur][(wm * 32 + mi * 16 + c) * 64 + g * 16];
        }
        #pragma unroll
        for (int ni = 0; ni < 2; ++ni) {
            bfr[ni] = *(const bf16x8*)&Br[cur][(wn * 32 + ni * 16 + c) * 64 + g * 16];
            bfs[ni] = *(const bf16x8*)&Bz[cur][(wn * 32 + ni * 16 + c) * 64 + g * 16];
        }
        #pragma unroll
        for (int mi = 0; mi < 2; ++mi)
            #pragma unroll
            for (int ni = 0; ni < 2; ++ni) {
                accr[mi][ni] = __builtin_amdgcn_mfma_f32_16x16x32_bf16(afr[mi], bfr[ni], accr[mi][ni], 0, 0, 0);
                accs[mi][ni] = __builtin_amdgcn_mfma_f32_16x16x32_bf16(afs[mi], bfs[ni], accs[mi][ni], 0, 0, 0);
            }
        cur = (cur + 1) % 3;
    }
    #pragma unroll
    for (int mi = 0; mi < 2; ++mi)
        #pragma unroll
        for (int ni = 0; ni < 2; ++ni)
            #pragma unroll
            for (int r = 0; r < 4; ++r) {
                int lr = wm * 32 + mi * 16 + 4 * g + r;
                if (m0 + lr >= ntok) continue;
                int token = rowid[lr];
                int bt = token >> 10, st = token & (SEQ - 1);
                size_t oo = (size_t)st * (BATCH * DM) + bt * DM + n0 + wn * 32 + ni * 16 + c;
                out[oo] = accr[mi][ni][r] * wtok[token] + accs[mi][ni][r];
            }
}

// ---------------------------------------------------------------------------
__global__ __launch_bounds__(256) void k_gate(
    const bf16* __restrict__ y, const float* __restrict__ gw,
    int* __restrict__ cnt, int* __restrict__ lists, float* __restrict__ wtok)
{
    int warp = threadIdx.x >> 6, lane = threadIdx.x & 63;
    int t = blockIdx.x * 4 + warp;
    float acc[NEXP] = {};
    for (int d = lane; d < DM; d += 64) {
        float xv = __bfloat162float(y[(size_t)t * DM + d]);
        #pragma unroll
        for (int e = 0; e < NEXP; ++e) acc[e] += xv * gw[e * DM + d];
    }
    #pragma unroll
    for (int off = 32; off; off >>= 1)
        #pragma unroll
        for (int e = 0; e < NEXP; ++e) acc[e] += __shfl_xor(acc[e], off);
    if (lane == 0) {
        float mx = fmaxf(fmaxf(acc[0], acc[1]), fmaxf(acc[2], acc[3]));
        float ex[NEXP], ssum = 0.f;
        #pragma unroll
        for (int e = 0; e < NEXP; ++e) { ex[e] = __expf(acc[e] - mx); ssum += ex[e]; }
        int best = 0; float bv = ex[0];
        #pragma unroll
        for (int e = 1; e < NEXP; ++e) if (ex[e] > bv) { bv = ex[e]; best = e; }
        wtok[t] = bv / ssum;
        int pos = atomicAdd(&cnt[best], 1);
        lists[best * T + pos] = t;
    }
}

// ---------------------------------------------------------------------------
extern "C" void kernel_launch(void* const* d_in, const int* in_sizes, int n_in,
                              void* d_out, int out_size, void* d_ws, size_t ws_size,
                              hipStream_t stream) {
    (void)in_sizes; (void)n_in; (void)out_size; (void)ws_size;
    const float* dec      = (const float*)d_in[0];
    const float* wq_a     = (const float*)d_in[1];
    const float* q_norm_w = (const float*)d_in[2];
    const float* wq_b     = (const float*)d_in[3];
    const float* wkv_a    = (const float*)d_in[4];
    const float* kv_norm_w= (const float*)d_in[5];
    const float* wkv_b    = (const float*)d_in[6];
    const float* wo       = (const float*)d_in[7];
    const float* gate_w   = (const float*)d_in[8];
    const float* exp_gate = (const float*)d_in[9];
    const float* exp_up   = (const float*)d_in[10];
    const float* exp_down = (const float*)d_in[11];
    const float* sh_gate  = (const float*)d_in[12];
    const float* sh_up    = (const float*)d_in[13];
    const float* sh_down  = (const float*)d_in[14];
    float* out = (float*)d_out;

    char* W = (char*)d_ws;
    bf16* qb   = (bf16*)(W);                    // 4MB; reused as y
    bf16* kb   = (bf16*)(W + (4ull  << 20));    // 4MB; reused as act_r
    bf16* vt_g = (bf16*)(W + (8ull  << 20));    // 4MB; reused as act_s
    char* SMALL = W + (12ull << 20);
    bf16* ab   = (bf16*)(W + (12ull << 20));    // 4MB (aliases SMALL, dead by then)
    bf16* woT = (bf16*)(W + (16ull << 20));
    bf16* sgT = (bf16*)(W + (18ull << 20));
    bf16* suT = (bf16*)(W + (20ull << 20));
    bf16* sdT = (bf16*)(W + (22ull << 20));
    bf16* egT = (bf16*)(W + (24ull << 20));
    bf16* euT = (bf16*)(W + (32ull << 20));
    bf16* edT = (bf16*)(W + (40ull << 20));
    int*   cnt   = (int*)(W + (48ull << 20));
    int*   lists = cnt + 16;
    float* wtok  = (float*)(lists + NEXP * T);
    bf16* yb    = qb;
    bf16* act_r = kb;
    bf16* act_s = vt_g;

    float* lora4 = (float*)(SMALL);
    bf16*  loraT = (bf16*) (SMALL + 1179648);
    bf16*  wqbT  = (bf16*) (SMALL + 1343488);
    bf16*  wkvbT = (bf16*) (SMALL + 1409024);
    bf16*  nrmq  = (bf16*) (SMALL + 1507328);
    bf16*  nrmkv = (bf16*) (SMALL + 1638400);
    float* ctab  = (float*)(SMALL + 1769472);
    float* stab  = (float*)(SMALL + 2818048);

    k_setup<<<dim3(32, 32, 20), 256, 0, stream>>>(
        wo, sh_gate, sh_up, sh_down, exp_gate, exp_up, exp_down,
        woT, sgT, suT, sdT, egT, euT, edT,
        wq_a, wkv_a, wq_b, wkv_b, loraT, wqbT, wkvbT, ctab, stab);

    k_p1<<<dim3(2, 16), 256, 0, stream>>>(dec, loraT, lora4);
    k_p2m<<<T, 256, 0, stream>>>(lora4, q_norm_w, kv_norm_w, ctab, stab,
                                 nrmq, nrmkv, kb, cnt);
    k_p3<<<dim3(24, 16, 2), 256, 0, stream>>>(nrmq, wqbT, nrmkv, wkvbT,
                                              ctab, stab, qb, kb, vt_g);

    k_attn<<<dim3(8, 32, BATCH), 256, 0, stream>>>(qb, kb, vt_g, ab);
    k_mm_plain<<<dim3(16, 16), 512, 0, stream>>>(ab, woT, yb);
    k_gate<<<T / 4, 256, 0, stream>>>(yb, gate_w, cnt, lists, wtok);
    k_mm_gu_all<<<dim3(8, 16, NEXP + 1), 512, 0, stream>>>(
        yb, egT, euT, sgT, suT, cnt, lists, act_r, act_s);
    k_mm_down_f<<<dim3(16, 16, NEXP), 512, 0, stream>>>(
        act_r, act_s, edT, sdT, cnt, lists, wtok, out);
}

// Round 17
// 172.445 us; speedup vs baseline: 1.0440x; 1.0440x over previous
//
#include <hip/hip_runtime.h>
#include <hip/hip_bf16.h>
#include <math.h>

#define SEQ 1024
#define BATCH 2
#define T 2048
#define DM 1024
#define NH 16
#define NOPE 32
#define HD 64
#define QL 20
#define KVL 20
#define KVA 52
#define HID 1024
#define NEXP 4
#define LSTR 80

typedef short bf16x8 __attribute__((ext_vector_type(8)));
typedef float f32x4 __attribute__((ext_vector_type(4)));
typedef float f32x16 __attribute__((ext_vector_type(16)));
typedef __hip_bfloat16 bf16;

static __device__ __forceinline__ float sigmoidf_(float x) {
    return 1.0f / (1.0f + __expf(-x));
}
static __device__ __forceinline__ unsigned short bfbits(float x) {
    bf16 h = __float2bfloat16(x);
    return *reinterpret_cast<unsigned short*>(&h);
}
static __device__ __forceinline__ unsigned cvt_pk_bf16(float lo, float hi) {
    unsigned r;
    asm("v_cvt_pk_bf16_f32 %0, %1, %2" : "=v"(r) : "v"(lo), "v"(hi));
    return r;
}
static __device__ __forceinline__ void gload16(const bf16* g, char* l) {
    __builtin_amdgcn_global_load_lds(
        (const __attribute__((address_space(1))) unsigned int*)g,
        (__attribute__((address_space(3))) unsigned int*)l, 16, 0, 0);
}
static __device__ __forceinline__ void barrier_() {
    asm volatile("" ::: "memory");
    __builtin_amdgcn_s_barrier();
    asm volatile("" ::: "memory");
}
#define VMWAIT(N) asm volatile("s_waitcnt vmcnt(" #N ")" ::: "memory")

// ---------------------------------------------------------------------------
// k_setup: all weight preprocessing in one launch.
// ---------------------------------------------------------------------------
__global__ __launch_bounds__(256) void k_setup(
    const float* __restrict__ wo, const float* __restrict__ sg,
    const float* __restrict__ su, const float* __restrict__ sd,
    const float* __restrict__ eg, const float* __restrict__ eu,
    const float* __restrict__ ed,
    bf16* __restrict__ woT, bf16* __restrict__ sgT, bf16* __restrict__ suT,
    bf16* __restrict__ sdT, bf16* __restrict__ egT, bf16* __restrict__ euT,
    bf16* __restrict__ edT,
    const float* __restrict__ wq_a, const float* __restrict__ wkv_a,
    const float* __restrict__ wq_b, const float* __restrict__ wkv_b,
    bf16* __restrict__ loraT, bf16* __restrict__ wqbT, bf16* __restrict__ wkvbT,
    float* __restrict__ ctab, float* __restrict__ stab)
{
    int z = blockIdx.z;
    int tid = threadIdx.x;
    if (z < 16) {
        __shared__ float tile[32][33];
        const float* in; bf16* out;
        if      (z == 0) { in = wo; out = woT; }
        else if (z == 1) { in = sg; out = sgT; }
        else if (z == 2) { in = su; out = suT; }
        else if (z == 3) { in = sd; out = sdT; }
        else if (z < 8)  { size_t o = (size_t)(z - 4)  * DM * HID; in = eg + o; out = egT + o; }
        else if (z < 12) { size_t o = (size_t)(z - 8)  * DM * HID; in = eu + o; out = euT + o; }
        else             { size_t o = (size_t)(z - 12) * HID * DM; in = ed + o; out = edT + o; }
        int c0 = blockIdx.x * 32, r0 = blockIdx.y * 32;
        int tx = tid & 31, ty = tid >> 5;
        #pragma unroll
        for (int ii = 0; ii < 4; ++ii)
            tile[ty + ii * 8][tx] = in[(size_t)(r0 + ty + ii * 8) * 1024 + c0 + tx];
        __syncthreads();
        int c = tid >> 3, rg = (tid & 7) * 4;
        ushort4 o4;
        o4.x = bfbits(tile[rg + 0][c]);
        o4.y = bfbits(tile[rg + 1][c]);
        o4.z = bfbits(tile[rg + 2][c]);
        o4.w = bfbits(tile[rg + 3][c]);
        *(ushort4*)&out[(size_t)(c0 + c) * 1024 + r0 + rg] = o4;
    } else if (z == 16) {
        int s = blockIdx.y * 32 + blockIdx.x;
        int p = tid;
        float freq = exp2f(-(float)p * (13.287712379549449f / 256.0f));
        float ang = (float)s * freq;
        float sn, cs;
        __sincosf(ang, &sn, &cs);
        ctab[s * 256 + p] = cs;
        stab[s * 256 + p] = sn;
    } else {
        int idx = (blockIdx.y * 32 + blockIdx.x) * 256 + tid;
        if (z == 17) {
            if (idx >= 80 * 1024) return;
            int n = idx >> 10, k = idx & 1023;
            float v = (n < 20) ? wq_a[k * QL + n] : (n < 72 ? wkv_a[k * KVA + (n - 20)] : 0.f);
            loraT[idx] = __float2bfloat16(v);
        } else if (z == 18) {
            if (idx >= 1024 * 32) return;
            int n = idx >> 5, k = idx & 31;
            wqbT[idx] = __float2bfloat16(k < 20 ? wq_b[k * DM + n] : 0.f);
        } else {
            if (idx >= 1536 * 32) return;
            int n = idx >> 5, k = idx & 31;
            wkvbT[idx] = __float2bfloat16(k < 20 ? wkv_b[k * (NH * 96) + n] : 0.f);
        }
    }
}

// ---------------------------------------------------------------------------
// k_p1: lora partials = dec @ [wq_a|wkv_a] via MFMA, kz in {0,1}.
// ---------------------------------------------------------------------------
__global__ __launch_bounds__(256) void k_p1(
    const float* __restrict__ dec, const bf16* __restrict__ loraT,
    float* __restrict__ lora4)
{
    __shared__ __align__(16) char As[128 * LSTR];
    __shared__ __align__(16) char Bs[80 * LSTR];
    const int tid = threadIdx.x;
    const int kz = blockIdx.x;
    const int m0 = blockIdx.y * 128;
    const int lane = tid & 63, wave = tid >> 6;
    const int g = lane >> 4, c = lane & 15;
    f32x4 acc[2][5] = {};
    for (int ks = 0; ks < 16; ++ks) {
        int k0 = kz * 512 + ks * 32;
        __syncthreads();
        #pragma unroll
        for (int pass = 0; pass < 4; ++pass) {
            int row = (tid >> 3) + pass * 32;
            int t = m0 + row;
            int b = t >> 10, s = t & 1023;
            f32x4 v = *(const f32x4*)&dec[(size_t)(s * 2 + b) * DM + k0 + (tid & 7) * 4];
            ushort4 h4;
            h4.x = bfbits(v[0]); h4.y = bfbits(v[1]);
            h4.z = bfbits(v[2]); h4.w = bfbits(v[3]);
            *(ushort4*)&As[row * LSTR + (tid & 7) * 8] = h4;
        }
        if (tid < 160) {
            int row = tid >> 1, hf = tid & 1;
            const bf16* src = &loraT[row * 1024 + k0 + hf * 16];
            *(int4*)&Bs[row * LSTR + hf * 32]      = *(const int4*)&src[0];
            *(int4*)&Bs[row * LSTR + hf * 32 + 16] = *(const int4*)&src[8];
        }
        __syncthreads();
        bf16x8 af[2], bff[5];
        #pragma unroll
        for (int mi = 0; mi < 2; ++mi)
            af[mi] = *(const bf16x8*)&As[(wave * 32 + mi * 16 + c) * LSTR + 16 * g];
        #pragma unroll
        for (int nf = 0; nf < 5; ++nf)
            bff[nf] = *(const bf16x8*)&Bs[(nf * 16 + c) * LSTR + 16 * g];
        #pragma unroll
        for (int mi = 0; mi < 2; ++mi)
            #pragma unroll
            for (int nf = 0; nf < 5; ++nf)
                acc[mi][nf] = __builtin_amdgcn_mfma_f32_16x16x32_bf16(af[mi], bff[nf], acc[mi][nf], 0, 0, 0);
    }
    #pragma unroll
    for (int mi = 0; mi < 2; ++mi)
        #pragma unroll
        for (int nf = 0; nf < 5; ++nf)
            #pragma unroll
            for (int r = 0; r < 4; ++r) {
                int col = nf * 16 + c;
                if (col < 72) {
                    int row = m0 + wave * 32 + mi * 16 + 4 * g + r;
                    lora4[((size_t)kz * T + row) * 72 + col] = acc[mi][nf][r];
                }
            }
}

// ---------------------------------------------------------------------------
// k_p2m: merged RMS (blocks 0..7) + k_pe RoPE (all T blocks).
// ---------------------------------------------------------------------------
__global__ __launch_bounds__(256) void k_p2m(
    const float* __restrict__ lora4, const float* __restrict__ qnw,
    const float* __restrict__ kvnw, const float* __restrict__ ctab,
    const float* __restrict__ stab, bf16* __restrict__ nrmq,
    bf16* __restrict__ nrmkv, bf16* __restrict__ kb, int* __restrict__ cnt)
{
    int bid = blockIdx.x, tid = threadIdx.x;
    if (bid == 0 && tid < 16) cnt[tid] = 0;
    {
        int t = bid, p = tid;
        int r = p & 15, h = p >> 4, s = t & (SEQ - 1);
        float y0 = lora4[t * 72 + 40 + 2 * r] + lora4[(size_t)(T + t) * 72 + 40 + 2 * r];
        float y1 = lora4[t * 72 + 41 + 2 * r] + lora4[(size_t)(T + t) * 72 + 41 + 2 * r];
        float cs = ctab[s * 256 + p], sn = stab[s * 256 + p];
        ushort2 pk;
        pk.x = bfbits(y0 * cs - y1 * sn);
        pk.y = bfbits(y0 * sn + y1 * cs);
        *(ushort2*)&kb[(size_t)t * DM + h * HD + NOPE + 2 * r] = pk;
    }
    if (bid < 8) {
        int t = bid * 256 + tid;
        float lq[20], lk[20];
        float ssq = 0.f, ssk = 0.f;
        #pragma unroll
        for (int i = 0; i < 20; ++i) {
            lq[i] = lora4[t * 72 + i] + lora4[(size_t)(T + t) * 72 + i];
            ssq += lq[i] * lq[i];
        }
        #pragma unroll
        for (int i = 0; i < 20; ++i) {
            lk[i] = lora4[t * 72 + 20 + i] + lora4[(size_t)(T + t) * 72 + 20 + i];
            ssk += lk[i] * lk[i];
        }
        float fq = rsqrtf(ssq / 20.f + 1e-6f);
        float fk = rsqrtf(ssk / 20.f + 1e-6f);
        #pragma unroll
        for (int i = 0; i < 32; ++i) {
            nrmq[t * 32 + i]  = __float2bfloat16(i < 20 ? lq[i] * fq * qnw[i]  : 0.f);
            nrmkv[t * 32 + i] = __float2bfloat16(i < 20 ? lk[i] * fk * kvnw[i] : 0.f);
        }
    }
}

// ---------------------------------------------------------------------------
// k_p3: merged q-expand (z=0) and kv-expand (z=1).
// ---------------------------------------------------------------------------
__global__ __launch_bounds__(256) void k_p3(
    const bf16* __restrict__ nrmq, const bf16* __restrict__ wqbT,
    const bf16* __restrict__ nrmkv, const bf16* __restrict__ wkvbT,
    const float* __restrict__ ctab, const float* __restrict__ stab,
    bf16* __restrict__ qb, bf16* __restrict__ kb, bf16* __restrict__ vt_g)
{
    const int zq = (blockIdx.z == 0);
    if (zq && blockIdx.x >= 16) return;
    __shared__ __align__(16) char As[128 * LSTR];
    __shared__ __align__(16) char Bs[64 * LSTR];
    const int tid = threadIdx.x;
    const int m0 = blockIdx.y * 128, n0 = blockIdx.x * 64;
    const int lane = tid & 63, wave = tid >> 6;
    const int g = lane >> 4, c = lane & 15;
    const int wm = wave >> 1, wn = wave & 1;
    const bf16* nrm = zq ? nrmq : nrmkv;
    const bf16* wT  = zq ? wqbT : wkvbT;
    {
        int row = tid >> 1, hf = tid & 1;
        const bf16* sa = &nrm[(size_t)(m0 + row) * 32 + hf * 16];
        *(int4*)&As[row * LSTR + hf * 32]      = *(const int4*)&sa[0];
        *(int4*)&As[row * LSTR + hf * 32 + 16] = *(const int4*)&sa[8];
        int brow = tid >> 2;
        *(int4*)&Bs[brow * LSTR + (tid & 3) * 16] = *(const int4*)&wT[(size_t)(n0 + brow) * 32 + (tid & 3) * 8];
    }
    __syncthreads();
    f32x4 acc[4][2] = {};
    bf16x8 af[4], bfr[2];
    #pragma unroll
    for (int mi = 0; mi < 4; ++mi)
        af[mi] = *(const bf16x8*)&As[(wm * 64 + mi * 16 + c) * LSTR + 16 * g];
    #pragma unroll
    for (int ni = 0; ni < 2; ++ni)
        bfr[ni] = *(const bf16x8*)&Bs[(wn * 32 + ni * 16 + c) * LSTR + 16 * g];
    #pragma unroll
    for (int mi = 0; mi < 4; ++mi)
        #pragma unroll
        for (int ni = 0; ni < 2; ++ni)
            acc[mi][ni] = __builtin_amdgcn_mfma_f32_16x16x32_bf16(af[mi], bfr[ni], acc[mi][ni], 0, 0, 0);

    if (zq) {
        #pragma unroll
        for (int mi = 0; mi < 4; ++mi)
            #pragma unroll
            for (int ni = 0; ni < 2; ++ni) {
                #pragma unroll
                for (int r = 0; r < 4; ++r) acc[mi][ni][r] *= 0.18033688f;  // 0.125*log2(e)
                int n = n0 + wn * 32 + ni * 16 + c;
                int w = n & 63;
                if (w < 32) {
                    #pragma unroll
                    for (int r = 0; r < 4; ++r) {
                        int row = m0 + wm * 64 + mi * 16 + 4 * g + r;
                        qb[(size_t)row * DM + n] = __float2bfloat16(acc[mi][ni][r]);
                    }
                } else {
                    int h = n >> 6;
                    int pidx = h * 16 + ((w - 32) >> 1);
                    int odd = w & 1;
                    #pragma unroll
                    for (int r = 0; r < 4; ++r) {
                        int row = m0 + wm * 64 + mi * 16 + 4 * g + r;
                        int s = row & (SEQ - 1);
                        float own = acc[mi][ni][r];
                        float oth = __shfl_xor(own, 1);
                        float cs = ctab[s * 256 + pidx], sn = stab[s * 256 + pidx];
                        float o = odd ? (oth * sn + own * cs) : (own * cs - oth * sn);
                        qb[(size_t)row * DM + n] = __float2bfloat16(o);
                    }
                }
            }
    } else {
        #pragma unroll
        for (int mi = 0; mi < 4; ++mi)
            #pragma unroll
            for (int ni = 0; ni < 2; ++ni) {
                int n = n0 + wn * 32 + ni * 16 + c;
                int h = n / 96, w = n - h * 96;
                int row0 = m0 + wm * 64 + mi * 16 + 4 * g;
                if (w < NOPE) {
                    #pragma unroll
                    for (int r = 0; r < 4; ++r)
                        kb[(size_t)(row0 + r) * DM + h * HD + w] = __float2bfloat16(acc[mi][ni][r]);
                } else {
                    int d = w - NOPE;
                    int b = row0 >> 10, s0 = row0 & (SEQ - 1);
                    ushort4 v4;
                    v4.x = bfbits(acc[mi][ni][0]);
                    v4.y = bfbits(acc[mi][ni][1]);
                    v4.z = bfbits(acc[mi][ni][2]);
                    v4.w = bfbits(acc[mi][ni][3]);
                    *(ushort4*)&vt_g[(((size_t)(b * NH + h) * HD + d) << 10) + s0] = v4;
                }
            }
    }
}

// ---------------------------------------------------------------------------
// k_attn: champion version (4 waves, 64 q rows, gload staging, LDS overlay).
// ---------------------------------------------------------------------------
__global__ __launch_bounds__(256) void k_attn(
    const bf16* __restrict__ qb, const bf16* __restrict__ kb,
    const bf16* __restrict__ vt_g, bf16* __restrict__ ab)
{
    __shared__ __align__(16) char stage[2][16384];

    const int orig = blockIdx.y * 8 + blockIdx.x;
    const int h  = (orig & 7) * 2 + ((orig >> 3) & 1);
    const int qt = orig >> 4;
    const int b = blockIdx.z;
    const int tid = threadIdx.x;
    const int lane = tid & 63, wave = tid >> 6;
    const int l31 = lane & 31, hi = lane >> 5;
    const int sp = wave >> 1, wq = wave & 1;
    const int q0 = qt * 64 + wq * 32;
    char* ks = stage[sp];
    char* vt = stage[sp] + 8192;

    const int scol = ((lane & 7) * 8) ^ ((lane >> 3) << 3);
    const int srowL = lane >> 3;

    bf16x8 qf[4];
    {
        const bf16* qrow = &qb[(size_t)(b * SEQ + q0 + l31) * DM + h * HD + 8 * hi];
        #pragma unroll
        for (int st = 0; st < 4; ++st)
            qf[st] = *(const bf16x8*)&qrow[16 * st];
    }

    f32x16 o0 = {}, o1 = {};
    float m_run = -3.0e38f, l_run = 0.f;
    const size_t vbase = ((size_t)(b * NH + h) * HD) << 10;

    for (int ktl = 0; ktl < 8; ++ktl) {
        const int kt = sp * 8 + ktl;
        __syncthreads();
        #pragma unroll
        for (int ps = 0; ps < 4; ++ps) {
            int rbase = ps * 16 + wq * 8;
            int row = rbase + srowL;
            gload16(&kb[(size_t)(b * SEQ + kt * 64 + row) * DM + h * HD + scol],
                    ks + rbase * 128);
            gload16(&vt_g[vbase + ((size_t)row << 10) + kt * 64 + scol],
                    vt + rbase * 128);
        }
        VMWAIT(0);
        __syncthreads();

        f32x16 sc0 = {}, sc1 = {};
        __builtin_amdgcn_s_setprio(1);
        #pragma unroll
        for (int st = 0; st < 4; ++st) {
            int colb = 32 * st + 16 * hi;
            int r0 = l31;
            bf16x8 kf0 = *(const bf16x8*)&ks[r0 * 128 + (colb ^ ((r0 & 7) << 4))];
            sc0 = __builtin_amdgcn_mfma_f32_32x32x16_bf16(kf0, qf[st], sc0, 0, 0, 0);
            int r1 = 32 + l31;
            bf16x8 kf1 = *(const bf16x8*)&ks[r1 * 128 + (colb ^ ((r1 & 7) << 4))];
            sc1 = __builtin_amdgcn_mfma_f32_32x32x16_bf16(kf1, qf[st], sc1, 0, 0, 0);
        }
        __builtin_amdgcn_s_setprio(0);

        float mt = fmaxf(sc0[0], sc1[0]);
        #pragma unroll
        for (int i = 1; i < 16; ++i) mt = fmaxf(mt, fmaxf(sc0[i], sc1[i]));
        mt = fmaxf(mt, __shfl_xor(mt, 32));

        if (!__all(mt <= m_run + 8.0f)) {
            float m_new = fmaxf(m_run, mt);
            float corr = exp2f(m_run - m_new);
            m_run = m_new;
            l_run *= corr;
            #pragma unroll
            for (int i = 0; i < 16; ++i) { o0[i] *= corr; o1[i] *= corr; }
        }
        float ls = 0.f;
        #pragma unroll
        for (int i = 0; i < 16; ++i) {
            sc0[i] = exp2f(sc0[i] - m_run);
            sc1[i] = exp2f(sc1[i] - m_run);
            ls += sc0[i] + sc1[i];
        }
        ls += __shfl_xor(ls, 32);
        l_run += ls;

        unsigned pk0[8], pk1[8];
        #pragma unroll
        for (int i = 0; i < 8; ++i) {
            pk0[i] = cvt_pk_bf16(sc0[2 * i], sc0[2 * i + 1]);
            pk1[i] = cvt_pk_bf16(sc1[2 * i], sc1[2 * i + 1]);
        }

        __builtin_amdgcn_s_setprio(1);
#define PV_SUB(PK, KK)                                                          \
        {                                                                       \
            _Pragma("unroll")                                                   \
            for (int s = 0; s < 2; ++s) {                                       \
                unsigned sx = hi ? PK[4*s]   : PK[4*s+2];                       \
                unsigned rx = __shfl_xor(sx, 32);                               \
                unsigned sy = hi ? PK[4*s+1] : PK[4*s+3];                       \
                unsigned ry = __shfl_xor(sy, 32);                               \
                int4 bi;                                                        \
                bi.x = hi ? (int)rx : (int)PK[4*s];                             \
                bi.y = hi ? (int)ry : (int)PK[4*s+1];                           \
                bi.z = hi ? (int)PK[4*s+2] : (int)rx;                           \
                bi.w = hi ? (int)PK[4*s+3] : (int)ry;                           \
                bf16x8 bfr = *(bf16x8*)&bi;                                     \
                int cb = (KK) * 64 + 32 * s + 16 * hi;                          \
                {                                                               \
                    int vr = l31;                                               \
                    bf16x8 vf = *(const bf16x8*)&vt[vr * 128 + (cb ^ ((vr & 7) << 4))]; \
                    o0 = __builtin_amdgcn_mfma_f32_32x32x16_bf16(vf, bfr, o0, 0, 0, 0); \
                }                                                               \
                {                                                               \
                    int vr = 32 + l31;                                          \
                    bf16x8 vf = *(const bf16x8*)&vt[vr * 128 + (cb ^ ((vr & 7) << 4))]; \
                    o1 = __builtin_amdgcn_mfma_f32_32x32x16_bf16(vf, bfr, o1, 0, 0, 0); \
                }                                                               \
            }                                                                   \
        }
        PV_SUB(pk0, 0)
        PV_SUB(pk1, 1)
#undef PV_SUB
        __builtin_amdgcn_s_setprio(0);
    }

    float* polB = (float*)stage[0];
    float* mllB = (float*)(stage[0] + 16640);

    __syncthreads();
    if (sp == 1) {
        #pragma unroll
        for (int i = 0; i < 16; ++i) {
            int d = (i & 3) + 8 * (i >> 2) + 4 * hi;
            polB[(wq * 32 + l31) * 65 + d]      = o0[i];
            polB[(wq * 32 + l31) * 65 + 32 + d] = o1[i];
        }
        if (hi == 0) {
            mllB[(wq * 32 + l31) * 2 + 0] = m_run;
            mllB[(wq * 32 + l31) * 2 + 1] = l_run;
        }
    }
    __syncthreads();
    if (sp == 0) {
        float m_b = mllB[(wq * 32 + l31) * 2 + 0];
        float l_b = mllB[(wq * 32 + l31) * 2 + 1];
        float M = fmaxf(m_run, m_b);
        float wa = exp2f(m_run - M), wb = exp2f(m_b - M);
        float inv = 1.0f / (l_run * wa + l_b * wb);
        #pragma unroll
        for (int i = 0; i < 16; ++i) {
            int d = (i & 3) + 8 * (i >> 2) + 4 * hi;
            o0[i] = (o0[i] * wa + polB[(wq * 32 + l31) * 65 + d]      * wb) * inv;
            o1[i] = (o1[i] * wa + polB[(wq * 32 + l31) * 65 + 32 + d] * wb) * inv;
        }
    }
    __syncthreads();
    if (sp == 0) {
        char* tb = stage[1] + (wq ? 8192 : 1024);
        #pragma unroll
        for (int i = 0; i < 8; ++i) {
            int dbase = 2 * (i & 1) + 8 * (i >> 1) + 4 * hi;
            *(unsigned*)&tb[l31 * 140 + (dbase) * 2]      = cvt_pk_bf16(o0[2 * i], o0[2 * i + 1]);
            *(unsigned*)&tb[l31 * 140 + (32 + dbase) * 2] = cvt_pk_bf16(o1[2 * i], o1[2 * i + 1]);
        }
        __builtin_amdgcn_s_waitcnt(0);
        #pragma unroll
        for (int p = 0; p < 8; ++p) {
            int idx = p * 64 + lane;
            int q = idx >> 4, c8 = idx & 15;
            int2 rv;
            rv.x = *(const int*)&tb[q * 140 + c8 * 8];
            rv.y = *(const int*)&tb[q * 140 + c8 * 8 + 4];
            *(int2*)&ab[(size_t)(b * SEQ + q0 + q) * DM + h * HD + c8 * 4] = rv;
        }
    }
}

// ---------------------------------------------------------------------------
// GEMM family: BK=32, 8 waves, gload16 staging, TRIPLE-buffered LDS ->
// one barrier per K-step. XCD-swizzled block mapping. (champion version)
// ---------------------------------------------------------------------------
__global__ __launch_bounds__(512) void k_mm_plain(
    const bf16* __restrict__ A, const bf16* __restrict__ Bt, bf16* __restrict__ C)
{
    __shared__ __align__(16) char As[3][8192];
    __shared__ __align__(16) char Bs[3][4096];
    const int tid = threadIdx.x;
    const int lane = tid & 63, wave = tid >> 6;
    const int g = lane >> 4, c = lane & 15;
    const int wm = wave >> 1, wn = wave & 1;
    int orig = blockIdx.y * 16 + blockIdx.x;
    int swz = (orig & 7) * 32 + (orig >> 3);
    const int n0 = (swz & 15) * 64, m0 = (swz >> 4) * 128;

    const int ldr = lane >> 2;
    const int ldc = (lane & 3) * 8;
    const bf16* agp = &A[(size_t)(m0 + wave * 16 + ldr) * DM + ldc];
    const bool doB = wave >= 4;
    const bf16* bgp = &Bt[(size_t)(n0 + (wave & 3) * 16 + ldr) * DM + ldc];
    const int aoffL = wave * 1024, boffL = (wave & 3) * 1024;

    f32x4 acc[2][2] = {};
    const int NT = DM / 32;
    gload16(agp, As[0] + aoffL);
    if (doB) gload16(bgp, Bs[0] + boffL);
    int cur = 0;
    for (int k = 0; k < NT; ++k) {
        if (k + 1 < NT) {
            int nxt = (cur + 1) % 3;
            gload16(agp + (k + 1) * 32, As[nxt] + aoffL);
            if (doB) gload16(bgp + (k + 1) * 32, Bs[nxt] + boffL);
            if (doB) VMWAIT(2); else VMWAIT(1);
        } else {
            VMWAIT(0);
        }
        barrier_();
        bf16x8 af[2], bfx[2];
        #pragma unroll
        for (int mi = 0; mi < 2; ++mi)
            af[mi] = *(const bf16x8*)&As[cur][(wm * 32 + mi * 16 + c) * 64 + g * 16];
        #pragma unroll
        for (int ni = 0; ni < 2; ++ni)
            bfx[ni] = *(const bf16x8*)&Bs[cur][(wn * 32 + ni * 16 + c) * 64 + g * 16];
        #pragma unroll
        for (int mi = 0; mi < 2; ++mi)
            #pragma unroll
            for (int ni = 0; ni < 2; ++ni)
                acc[mi][ni] = __builtin_amdgcn_mfma_f32_16x16x32_bf16(af[mi], bfx[ni], acc[mi][ni], 0, 0, 0);
        cur = (cur + 1) % 3;
    }
    #pragma unroll
    for (int mi = 0; mi < 2; ++mi)
        #pragma unroll
        for (int ni = 0; ni < 2; ++ni)
            #pragma unroll
            for (int r = 0; r < 4; ++r)
                C[(size_t)(m0 + wm * 32 + mi * 16 + 4 * g + r) * DM + n0 + wn * 32 + ni * 16 + c]
                    = __float2bfloat16(acc[mi][ni][r]);
}

// merged routed (z=0..3) + shared (z=4) gate+up, triple-buffered
__global__ __launch_bounds__(512) void k_mm_gu_all(
    const bf16* __restrict__ X, const bf16* __restrict__ egT,
    const bf16* __restrict__ euT, const bf16* __restrict__ sgT,
    const bf16* __restrict__ suT, const int* __restrict__ cnt,
    const int* __restrict__ lists, bf16* __restrict__ act_r,
    bf16* __restrict__ act_s)
{
    const int e = blockIdx.z;
    const bool SH = (e == 4);
    const int ntok = SH ? T : cnt[e];
    int orig = blockIdx.y * 16 + blockIdx.x;
    int swz = (orig & 7) * 32 + (orig >> 3);
    const int n0 = (swz & 15) * 64, m0 = (swz >> 4) * 128;
    if (m0 >= ntok) return;
    __shared__ __align__(16) char As[3][8192];
    __shared__ __align__(16) char Bg[3][4096];
    __shared__ __align__(16) char Bu[3][4096];
    __shared__ int rowid[128];
    const int tid = threadIdx.x;
    if (tid < 128) {
        int idx = m0 + tid;
        rowid[tid] = SH ? idx : lists[e * T + (idx < ntok ? idx : ntok - 1)];
    }
    __syncthreads();
    const int lane = tid & 63, wave = tid >> 6;
    const int g = lane >> 4, c = lane & 15;
    const int wm = wave >> 1, wn = wave & 1;
    const bf16* Bge = SH ? sgT : egT + (size_t)e * HID * DM;
    const bf16* Bue = SH ? suT : euT + (size_t)e * HID * DM;
    bf16* act = SH ? act_s : act_r;

    const int ldr = lane >> 2;
    const int ldc = (lane & 3) * 8;
    const int myTok = rowid[wave * 16 + ldr];
    const bf16* agp = &X[(size_t)myTok * DM + ldc];
    const bool isG = wave < 4;
    const bf16* bgp = (isG ? Bge : Bue) + (size_t)(n0 + (wave & 3) * 16 + ldr) * DM + ldc;
    const int aoffL = wave * 1024, boffL = (wave & 3) * 1024;

    f32x4 accg[2][2] = {}, accu[2][2] = {};
    const int NT = DM / 32;
    gload16(agp, As[0] + aoffL);
    gload16(bgp, (isG ? Bg[0] : Bu[0]) + boffL);
    int cur = 0;
    for (int k = 0; k < NT; ++k) {
        if (k + 1 < NT) {
            int nxt = (cur + 1) % 3;
            gload16(agp + (k + 1) * 32, As[nxt] + aoffL);
            gload16(bgp + (k + 1) * 32, (isG ? Bg[nxt] : Bu[nxt]) + boffL);
            VMWAIT(2);
        } else {
            VMWAIT(0);
        }
        barrier_();
        bf16x8 af[2], gf[2], uf[2];
        #pragma unroll
        for (int mi = 0; mi < 2; ++mi)
            af[mi] = *(const bf16x8*)&As[cur][(wm * 32 + mi * 16 + c) * 64 + g * 16];
        #pragma unroll
        for (int ni = 0; ni < 2; ++ni) {
            gf[ni] = *(const bf16x8*)&Bg[cur][(wn * 32 + ni * 16 + c) * 64 + g * 16];
            uf[ni] = *(const bf16x8*)&Bu[cur][(wn * 32 + ni * 16 + c) * 64 + g * 16];
        }
        #pragma unroll
        for (int mi = 0; mi < 2; ++mi)
            #pragma unroll
            for (int ni = 0; ni < 2; ++ni) {
                accg[mi][ni] = __builtin_amdgcn_mfma_f32_16x16x32_bf16(af[mi], gf[ni], accg[mi][ni], 0, 0, 0);
                accu[mi][ni] = __builtin_amdgcn_mfma_f32_16x16x32_bf16(af[mi], uf[ni], accu[mi][ni], 0, 0, 0);
            }
        cur = (cur + 1) % 3;
    }
    #pragma unroll
    for (int mi = 0; mi < 2; ++mi)
        #pragma unroll
        for (int ni = 0; ni < 2; ++ni)
            #pragma unroll
            for (int r = 0; r < 4; ++r) {
                int lr = wm * 32 + mi * 16 + 4 * g + r;
                if (!SH && m0 + lr >= ntok) continue;
                int token = rowid[lr];
                float gv = accg[mi][ni][r], uv = accu[mi][ni][r];
                act[(size_t)token * HID + n0 + wn * 32 + ni * 16 + c] =
                    __float2bfloat16(gv * sigmoidf_(gv) * uv);
            }
}

// fused down: out = (act_r @ exp_down[e]) * wtok + (act_s @ sh_down), tri-buffered
__global__ __launch_bounds__(512) void k_mm_down_f(
    const bf16* __restrict__ Xr, const bf16* __restrict__ Xs,
    const bf16* __restrict__ edT, const bf16* __restrict__ sdT,
    const int* __restrict__ cnt, const int* __restrict__ lists,
    const float* __restrict__ wtok, float* __restrict__ out)
{
    const int e = blockIdx.z;
    const int ntok = cnt[e];
    int orig = blockIdx.y * 16 + blockIdx.x;
    int swz = (orig & 7) * 32 + (orig >> 3);
    const int n0 = (swz & 15) * 64, m0 = (swz >> 4) * 128;
    if (m0 >= ntok) return;
    __shared__ __align__(16) char Ar[3][8192];
    __shared__ __align__(16) char Az[3][8192];
    __shared__ __align__(16) char Br[3][4096];
    __shared__ __align__(16) char Bz[3][4096];
    __shared__ int rowid[128];
    const int tid = threadIdx.x;
    if (tid < 128) {
        int idx = m0 + tid;
        rowid[tid] = lists[e * T + (idx < ntok ? idx : ntok - 1)];
    }
    __syncthreads();
    const int lane = tid & 63, wave = tid >> 6;
    const int g = lane >> 4, c = lane & 15;
    const int wm = wave >> 1, wn = wave & 1;
    const bf16* Bde = edT + (size_t)e * HID * DM;

    const int ldr = lane >> 2;
    const int ldc = (lane & 3) * 8;
    const int myTok = rowid[wave * 16 + ldr];
    const bf16* agr = &Xr[(size_t)myTok * HID + ldc];
    const bf16* ags = &Xs[(size_t)myTok * HID + ldc];
    const bool isR = wave < 4;
    const bf16* bgp = (isR ? Bde : sdT) + (size_t)(n0 + (wave & 3) * 16 + ldr) * HID + ldc;
    const int aoffL = wave * 1024, boffL = (wave & 3) * 1024;

    f32x4 accr[2][2] = {}, accs[2][2] = {};
    const int NT = HID / 32;
    gload16(agr, Ar[0] + aoffL);
    gload16(ags, Az[0] + aoffL);
    gload16(bgp, (isR ? Br[0] : Bz[0]) + boffL);
    int cur = 0;
    for (int k = 0; k < NT; ++k) {
        if (k + 1 < NT) {
            int nxt = (cur + 1) % 3;
            gload16(agr + (k + 1) * 32, Ar[nxt] + aoffL);
            gload16(ags + (k + 1) * 32, Az[nxt] + aoffL);
            gload16(bgp + (k + 1) * 32, (isR ? Br[nxt] : Bz[nxt]) + boffL);
            VMWAIT(3);
        } else {
            VMWAIT(0);
        }
        barrier_();
        bf16x8 afr[2], afs[2], bfr[2], bfs[2];
        #pragma unroll
        for (int mi = 0; mi < 2; ++mi) {
            afr[mi] = *(const bf16x8*)&Ar[cur][(wm * 32 + mi * 16 + c) * 64 + g * 16];
            afs[mi] = *(const bf16x8*)&Az[cur][(wm * 32 + mi * 16 + c) * 64 + g * 16];
        }
        #pragma unroll
        for (int ni = 0; ni < 2; ++ni) {
            bfr[ni] = *(const bf16x8*)&Br[cur][(wn * 32 + ni * 16 + c) * 64 + g * 16];
            bfs[ni] = *(const bf16x8*)&Bz[cur][(wn * 32 + ni * 16 + c) * 64 + g * 16];
        }
        #pragma unroll
        for (int mi = 0; mi < 2; ++mi)
            #pragma unroll
            for (int ni = 0; ni < 2; ++ni) {
                accr[mi][ni] = __builtin_amdgcn_mfma_f32_16x16x32_bf16(afr[mi], bfr[ni], accr[mi][ni], 0, 0, 0);
                accs[mi][ni] = __builtin_amdgcn_mfma_f32_16x16x32_bf16(afs[mi], bfs[ni], accs[mi][ni], 0, 0, 0);
            }
        cur = (cur + 1) % 3;
    }
    #pragma unroll
    for (int mi = 0; mi < 2; ++mi)
        #pragma unroll
        for (int ni = 0; ni < 2; ++ni)
            #pragma unroll
            for (int r = 0; r < 4; ++r) {
                int lr = wm * 32 + mi * 16 + 4 * g + r;
                if (m0 + lr >= ntok) continue;
                int token = rowid[lr];
                int bt = token >> 10, st = token & (SEQ - 1);
                size_t oo = (size_t)st * (BATCH * DM) + bt * DM + n0 + wn * 32 + ni * 16 + c;
                out[oo] = accr[mi][ni][r] * wtok[token] + accs[mi][ni][r];
            }
}

// ---------------------------------------------------------------------------
__global__ __launch_bounds__(256) void k_gate(
    const bf16* __restrict__ y, const float* __restrict__ gw,
    int* __restrict__ cnt, int* __restrict__ lists, float* __restrict__ wtok)
{
    int warp = threadIdx.x >> 6, lane = threadIdx.x & 63;
    int t = blockIdx.x * 4 + warp;
    float acc[NEXP] = {};
    for (int d = lane; d < DM; d += 64) {
        float xv = __bfloat162float(y[(size_t)t * DM + d]);
        #pragma unroll
        for (int e = 0; e < NEXP; ++e) acc[e] += xv * gw[e * DM + d];
    }
    #pragma unroll
    for (int off = 32; off; off >>= 1)
        #pragma unroll
        for (int e = 0; e < NEXP; ++e) acc[e] += __shfl_xor(acc[e], off);
    if (lane == 0) {
        float mx = fmaxf(fmaxf(acc[0], acc[1]), fmaxf(acc[2], acc[3]));
        float ex[NEXP], ssum = 0.f;
        #pragma unroll
        for (int e = 0; e < NEXP; ++e) { ex[e] = __expf(acc[e] - mx); ssum += ex[e]; }
        int best = 0; float bv = ex[0];
        #pragma unroll
        for (int e = 1; e < NEXP; ++e) if (ex[e] > bv) { bv = ex[e]; best = e; }
        wtok[t] = bv / ssum;
        int pos = atomicAdd(&cnt[best], 1);
        lists[best * T + pos] = t;
    }
}

// ---------------------------------------------------------------------------
extern "C" void kernel_launch(void* const* d_in, const int* in_sizes, int n_in,
                              void* d_out, int out_size, void* d_ws, size_t ws_size,
                              hipStream_t stream) {
    (void)in_sizes; (void)n_in; (void)out_size; (void)ws_size;
    const float* dec      = (const float*)d_in[0];
    const float* wq_a     = (const float*)d_in[1];
    const float* q_norm_w = (const float*)d_in[2];
    const float* wq_b     = (const float*)d_in[3];
    const float* wkv_a    = (const float*)d_in[4];
    const float* kv_norm_w= (const float*)d_in[5];
    const float* wkv_b    = (const float*)d_in[6];
    const float* wo       = (const float*)d_in[7];
    const float* gate_w   = (const float*)d_in[8];
    const float* exp_gate = (const float*)d_in[9];
    const float* exp_up   = (const float*)d_in[10];
    const float* exp_down = (const float*)d_in[11];
    const float* sh_gate  = (const float*)d_in[12];
    const float* sh_up    = (const float*)d_in[13];
    const float* sh_down  = (const float*)d_in[14];
    float* out = (float*)d_out;

    char* W = (char*)d_ws;
    bf16* qb   = (bf16*)(W);                    // 4MB; reused as y
    bf16* kb   = (bf16*)(W + (4ull  << 20));    // 4MB; reused as act_r
    bf16* vt_g = (bf16*)(W + (8ull  << 20));    // 4MB; reused as act_s
    char* SMALL = W + (12ull << 20);
    bf16* ab   = (bf16*)(W + (12ull << 20));    // 4MB (aliases SMALL, dead by then)
    bf16* woT = (bf16*)(W + (16ull << 20));
    bf16* sgT = (bf16*)(W + (18ull << 20));
    bf16* suT = (bf16*)(W + (20ull << 20));
    bf16* sdT = (bf16*)(W + (22ull << 20));
    bf16* egT = (bf16*)(W + (24ull << 20));
    bf16* euT = (bf16*)(W + (32ull << 20));
    bf16* edT = (bf16*)(W + (40ull << 20));
    int*   cnt   = (int*)(W + (48ull << 20));
    int*   lists = cnt + 16;
    float* wtok  = (float*)(lists + NEXP * T);
    bf16* yb    = qb;
    bf16* act_r = kb;
    bf16* act_s = vt_g;

    float* lora4 = (float*)(SMALL);
    bf16*  loraT = (bf16*) (SMALL + 1179648);
    bf16*  wqbT  = (bf16*) (SMALL + 1343488);
    bf16*  wkvbT = (bf16*) (SMALL + 1409024);
    bf16*  nrmq  = (bf16*) (SMALL + 1507328);
    bf16*  nrmkv = (bf16*) (SMALL + 1638400);
    float* ctab  = (float*)(SMALL + 1769472);
    float* stab  = (float*)(SMALL + 2818048);

    k_setup<<<dim3(32, 32, 20), 256, 0, stream>>>(
        wo, sh_gate, sh_up, sh_down, exp_gate, exp_up, exp_down,
        woT, sgT, suT, sdT, egT, euT, edT,
        wq_a, wkv_a, wq_b, wkv_b, loraT, wqbT, wkvbT, ctab, stab);

    k_p1<<<dim3(2, 16), 256, 0, stream>>>(dec, loraT, lora4);
    k_p2m<<<T, 256, 0, stream>>>(lora4, q_norm_w, kv_norm_w, ctab, stab,
                                 nrmq, nrmkv, kb, cnt);
    k_p3<<<dim3(24, 16, 2), 256, 0, stream>>>(nrmq, wqbT, nrmkv, wkvbT,
                                              ctab, stab, qb, kb, vt_g);

    k_attn<<<dim3(8, 32, BATCH), 256, 0, stream>>>(qb, kb, vt_g, ab);
    k_mm_plain<<<dim3(16, 16), 512, 0, stream>>>(ab, woT, yb);
    k_gate<<<T / 4, 256, 0, stream>>>(yb, gate_w, cnt, lists, wtok);
    k_mm_gu_all<<<dim3(16, 16, NEXP + 1), 512, 0, stream>>>(
        yb, egT, euT, sgT, suT, cnt, lists, act_r, act_s);
    k_mm_down_f<<<dim3(16, 16, NEXP), 512, 0, stream>>>(
        act_r, act_s, edT, sdT, cnt, lists, wtok, out);
}

// Round 18
// 172.095 us; speedup vs baseline: 1.0461x; 1.0020x over previous
//
#include <hip/hip_runtime.h>
#include <hip/hip_bf16.h>
#include <math.h>

#define SEQ 1024
#define BATCH 2
#define T 2048
#define DM 1024
#define NH 16
#define NOPE 32
#define HD 64
#define QL 20
#define KVL 20
#define KVA 52
#define HID 1024
#define NEXP 4
#define LSTR 80

typedef short bf16x8 __attribute__((ext_vector_type(8)));
typedef float f32x4 __attribute__((ext_vector_type(4)));
typedef float f32x16 __attribute__((ext_vector_type(16)));
typedef __hip_bfloat16 bf16;

static __device__ __forceinline__ float sigmoidf_(float x) {
    return 1.0f / (1.0f + __expf(-x));
}
static __device__ __forceinline__ unsigned short bfbits(float x) {
    bf16 h = __float2bfloat16(x);
    return *reinterpret_cast<unsigned short*>(&h);
}
static __device__ __forceinline__ unsigned cvt_pk_bf16(float lo, float hi) {
    unsigned r;
    asm("v_cvt_pk_bf16_f32 %0, %1, %2" : "=v"(r) : "v"(lo), "v"(hi));
    return r;
}
static __device__ __forceinline__ void gload16(const bf16* g, char* l) {
    __builtin_amdgcn_global_load_lds(
        (const __attribute__((address_space(1))) unsigned int*)g,
        (__attribute__((address_space(3))) unsigned int*)l, 16, 0, 0);
}
static __device__ __forceinline__ void barrier_() {
    asm volatile("" ::: "memory");
    __builtin_amdgcn_s_barrier();
    asm volatile("" ::: "memory");
}
#define VMWAIT(N) asm volatile("s_waitcnt vmcnt(" #N ")" ::: "memory")

// ---------------------------------------------------------------------------
// k_setup: all weight preprocessing in one launch.
// ---------------------------------------------------------------------------
__global__ __launch_bounds__(256) void k_setup(
    const float* __restrict__ wo, const float* __restrict__ sg,
    const float* __restrict__ su, const float* __restrict__ sd,
    const float* __restrict__ eg, const float* __restrict__ eu,
    const float* __restrict__ ed,
    bf16* __restrict__ woT, bf16* __restrict__ sgT, bf16* __restrict__ suT,
    bf16* __restrict__ sdT, bf16* __restrict__ egT, bf16* __restrict__ euT,
    bf16* __restrict__ edT,
    const float* __restrict__ wq_a, const float* __restrict__ wkv_a,
    const float* __restrict__ wq_b, const float* __restrict__ wkv_b,
    bf16* __restrict__ loraT, bf16* __restrict__ wqbT, bf16* __restrict__ wkvbT,
    float* __restrict__ ctab, float* __restrict__ stab)
{
    int z = blockIdx.z;
    int tid = threadIdx.x;
    if (z < 16) {
        __shared__ float tile[32][33];
        const float* in; bf16* out;
        if      (z == 0) { in = wo; out = woT; }
        else if (z == 1) { in = sg; out = sgT; }
        else if (z == 2) { in = su; out = suT; }
        else if (z == 3) { in = sd; out = sdT; }
        else if (z < 8)  { size_t o = (size_t)(z - 4)  * DM * HID; in = eg + o; out = egT + o; }
        else if (z < 12) { size_t o = (size_t)(z - 8)  * DM * HID; in = eu + o; out = euT + o; }
        else             { size_t o = (size_t)(z - 12) * HID * DM; in = ed + o; out = edT + o; }
        int c0 = blockIdx.x * 32, r0 = blockIdx.y * 32;
        int tx = tid & 31, ty = tid >> 5;
        #pragma unroll
        for (int ii = 0; ii < 4; ++ii)
            tile[ty + ii * 8][tx] = in[(size_t)(r0 + ty + ii * 8) * 1024 + c0 + tx];
        __syncthreads();
        int c = tid >> 3, rg = (tid & 7) * 4;
        ushort4 o4;
        o4.x = bfbits(tile[rg + 0][c]);
        o4.y = bfbits(tile[rg + 1][c]);
        o4.z = bfbits(tile[rg + 2][c]);
        o4.w = bfbits(tile[rg + 3][c]);
        *(ushort4*)&out[(size_t)(c0 + c) * 1024 + r0 + rg] = o4;
    } else if (z == 16) {
        int s = blockIdx.y * 32 + blockIdx.x;
        int p = tid;
        float freq = exp2f(-(float)p * (13.287712379549449f / 256.0f));
        float ang = (float)s * freq;
        float sn, cs;
        __sincosf(ang, &sn, &cs);
        ctab[s * 256 + p] = cs;
        stab[s * 256 + p] = sn;
    } else {
        int idx = (blockIdx.y * 32 + blockIdx.x) * 256 + tid;
        if (z == 17) {
            if (idx >= 80 * 1024) return;
            int n = idx >> 10, k = idx & 1023;
            float v = (n < 20) ? wq_a[k * QL + n] : (n < 72 ? wkv_a[k * KVA + (n - 20)] : 0.f);
            loraT[idx] = __float2bfloat16(v);
        } else if (z == 18) {
            if (idx >= 1024 * 32) return;
            int n = idx >> 5, k = idx & 31;
            wqbT[idx] = __float2bfloat16(k < 20 ? wq_b[k * DM + n] : 0.f);
        } else {
            if (idx >= 1536 * 32) return;
            int n = idx >> 5, k = idx & 31;
            wkvbT[idx] = __float2bfloat16(k < 20 ? wkv_b[k * (NH * 96) + n] : 0.f);
        }
    }
}

// ---------------------------------------------------------------------------
// k_p1: lora partials = dec @ [wq_a|wkv_a] via MFMA, kz in {0,1}.
// ---------------------------------------------------------------------------
__global__ __launch_bounds__(256) void k_p1(
    const float* __restrict__ dec, const bf16* __restrict__ loraT,
    float* __restrict__ lora4)
{
    __shared__ __align__(16) char As[128 * LSTR];
    __shared__ __align__(16) char Bs[80 * LSTR];
    const int tid = threadIdx.x;
    const int kz = blockIdx.x;
    const int m0 = blockIdx.y * 128;
    const int lane = tid & 63, wave = tid >> 6;
    const int g = lane >> 4, c = lane & 15;
    f32x4 acc[2][5] = {};
    for (int ks = 0; ks < 16; ++ks) {
        int k0 = kz * 512 + ks * 32;
        __syncthreads();
        #pragma unroll
        for (int pass = 0; pass < 4; ++pass) {
            int row = (tid >> 3) + pass * 32;
            int t = m0 + row;
            int b = t >> 10, s = t & 1023;
            f32x4 v = *(const f32x4*)&dec[(size_t)(s * 2 + b) * DM + k0 + (tid & 7) * 4];
            ushort4 h4;
            h4.x = bfbits(v[0]); h4.y = bfbits(v[1]);
            h4.z = bfbits(v[2]); h4.w = bfbits(v[3]);
            *(ushort4*)&As[row * LSTR + (tid & 7) * 8] = h4;
        }
        if (tid < 160) {
            int row = tid >> 1, hf = tid & 1;
            const bf16* src = &loraT[row * 1024 + k0 + hf * 16];
            *(int4*)&Bs[row * LSTR + hf * 32]      = *(const int4*)&src[0];
            *(int4*)&Bs[row * LSTR + hf * 32 + 16] = *(const int4*)&src[8];
        }
        __syncthreads();
        bf16x8 af[2], bff[5];
        #pragma unroll
        for (int mi = 0; mi < 2; ++mi)
            af[mi] = *(const bf16x8*)&As[(wave * 32 + mi * 16 + c) * LSTR + 16 * g];
        #pragma unroll
        for (int nf = 0; nf < 5; ++nf)
            bff[nf] = *(const bf16x8*)&Bs[(nf * 16 + c) * LSTR + 16 * g];
        #pragma unroll
        for (int mi = 0; mi < 2; ++mi)
            #pragma unroll
            for (int nf = 0; nf < 5; ++nf)
                acc[mi][nf] = __builtin_amdgcn_mfma_f32_16x16x32_bf16(af[mi], bff[nf], acc[mi][nf], 0, 0, 0);
    }
    #pragma unroll
    for (int mi = 0; mi < 2; ++mi)
        #pragma unroll
        for (int nf = 0; nf < 5; ++nf)
            #pragma unroll
            for (int r = 0; r < 4; ++r) {
                int col = nf * 16 + c;
                if (col < 72) {
                    int row = m0 + wave * 32 + mi * 16 + 4 * g + r;
                    lora4[((size_t)kz * T + row) * 72 + col] = acc[mi][nf][r];
                }
            }
}

// ---------------------------------------------------------------------------
// k_p2m: merged RMS (blocks 0..7) + k_pe RoPE (all T blocks).
// ---------------------------------------------------------------------------
__global__ __launch_bounds__(256) void k_p2m(
    const float* __restrict__ lora4, const float* __restrict__ qnw,
    const float* __restrict__ kvnw, const float* __restrict__ ctab,
    const float* __restrict__ stab, bf16* __restrict__ nrmq,
    bf16* __restrict__ nrmkv, bf16* __restrict__ kb, int* __restrict__ cnt)
{
    int bid = blockIdx.x, tid = threadIdx.x;
    if (bid == 0 && tid < 16) cnt[tid] = 0;
    {
        int t = bid, p = tid;
        int r = p & 15, h = p >> 4, s = t & (SEQ - 1);
        float y0 = lora4[t * 72 + 40 + 2 * r] + lora4[(size_t)(T + t) * 72 + 40 + 2 * r];
        float y1 = lora4[t * 72 + 41 + 2 * r] + lora4[(size_t)(T + t) * 72 + 41 + 2 * r];
        float cs = ctab[s * 256 + p], sn = stab[s * 256 + p];
        ushort2 pk;
        pk.x = bfbits(y0 * cs - y1 * sn);
        pk.y = bfbits(y0 * sn + y1 * cs);
        *(ushort2*)&kb[(size_t)t * DM + h * HD + NOPE + 2 * r] = pk;
    }
    if (bid < 8) {
        int t = bid * 256 + tid;
        float lq[20], lk[20];
        float ssq = 0.f, ssk = 0.f;
        #pragma unroll
        for (int i = 0; i < 20; ++i) {
            lq[i] = lora4[t * 72 + i] + lora4[(size_t)(T + t) * 72 + i];
            ssq += lq[i] * lq[i];
        }
        #pragma unroll
        for (int i = 0; i < 20; ++i) {
            lk[i] = lora4[t * 72 + 20 + i] + lora4[(size_t)(T + t) * 72 + 20 + i];
            ssk += lk[i] * lk[i];
        }
        float fq = rsqrtf(ssq / 20.f + 1e-6f);
        float fk = rsqrtf(ssk / 20.f + 1e-6f);
        #pragma unroll
        for (int i = 0; i < 32; ++i) {
            nrmq[t * 32 + i]  = __float2bfloat16(i < 20 ? lq[i] * fq * qnw[i]  : 0.f);
            nrmkv[t * 32 + i] = __float2bfloat16(i < 20 ? lk[i] * fk * kvnw[i] : 0.f);
        }
    }
}

// ---------------------------------------------------------------------------
// k_p3: merged q-expand (z=0) and kv-expand (z=1).
// ---------------------------------------------------------------------------
__global__ __launch_bounds__(256) void k_p3(
    const bf16* __restrict__ nrmq, const bf16* __restrict__ wqbT,
    const bf16* __restrict__ nrmkv, const bf16* __restrict__ wkvbT,
    const float* __restrict__ ctab, const float* __restrict__ stab,
    bf16* __restrict__ qb, bf16* __restrict__ kb, bf16* __restrict__ vt_g)
{
    const int zq = (blockIdx.z == 0);
    if (zq && blockIdx.x >= 16) return;
    __shared__ __align__(16) char As[128 * LSTR];
    __shared__ __align__(16) char Bs[64 * LSTR];
    const int tid = threadIdx.x;
    const int m0 = blockIdx.y * 128, n0 = blockIdx.x * 64;
    const int lane = tid & 63, wave = tid >> 6;
    const int g = lane >> 4, c = lane & 15;
    const int wm = wave >> 1, wn = wave & 1;
    const bf16* nrm = zq ? nrmq : nrmkv;
    const bf16* wT  = zq ? wqbT : wkvbT;
    {
        int row = tid >> 1, hf = tid & 1;
        const bf16* sa = &nrm[(size_t)(m0 + row) * 32 + hf * 16];
        *(int4*)&As[row * LSTR + hf * 32]      = *(const int4*)&sa[0];
        *(int4*)&As[row * LSTR + hf * 32 + 16] = *(const int4*)&sa[8];
        int brow = tid >> 2;
        *(int4*)&Bs[brow * LSTR + (tid & 3) * 16] = *(const int4*)&wT[(size_t)(n0 + brow) * 32 + (tid & 3) * 8];
    }
    __syncthreads();
    f32x4 acc[4][2] = {};
    bf16x8 af[4], bfr[2];
    #pragma unroll
    for (int mi = 0; mi < 4; ++mi)
        af[mi] = *(const bf16x8*)&As[(wm * 64 + mi * 16 + c) * LSTR + 16 * g];
    #pragma unroll
    for (int ni = 0; ni < 2; ++ni)
        bfr[ni] = *(const bf16x8*)&Bs[(wn * 32 + ni * 16 + c) * LSTR + 16 * g];
    #pragma unroll
    for (int mi = 0; mi < 4; ++mi)
        #pragma unroll
        for (int ni = 0; ni < 2; ++ni)
            acc[mi][ni] = __builtin_amdgcn_mfma_f32_16x16x32_bf16(af[mi], bfr[ni], acc[mi][ni], 0, 0, 0);

    if (zq) {
        #pragma unroll
        for (int mi = 0; mi < 4; ++mi)
            #pragma unroll
            for (int ni = 0; ni < 2; ++ni) {
                #pragma unroll
                for (int r = 0; r < 4; ++r) acc[mi][ni][r] *= 0.18033688f;  // 0.125*log2(e)
                int n = n0 + wn * 32 + ni * 16 + c;
                int w = n & 63;
                if (w < 32) {
                    #pragma unroll
                    for (int r = 0; r < 4; ++r) {
                        int row = m0 + wm * 64 + mi * 16 + 4 * g + r;
                        qb[(size_t)row * DM + n] = __float2bfloat16(acc[mi][ni][r]);
                    }
                } else {
                    int h = n >> 6;
                    int pidx = h * 16 + ((w - 32) >> 1);
                    int odd = w & 1;
                    #pragma unroll
                    for (int r = 0; r < 4; ++r) {
                        int row = m0 + wm * 64 + mi * 16 + 4 * g + r;
                        int s = row & (SEQ - 1);
                        float own = acc[mi][ni][r];
                        float oth = __shfl_xor(own, 1);
                        float cs = ctab[s * 256 + pidx], sn = stab[s * 256 + pidx];
                        float o = odd ? (oth * sn + own * cs) : (own * cs - oth * sn);
                        qb[(size_t)row * DM + n] = __float2bfloat16(o);
                    }
                }
            }
    } else {
        #pragma unroll
        for (int mi = 0; mi < 4; ++mi)
            #pragma unroll
            for (int ni = 0; ni < 2; ++ni) {
                int n = n0 + wn * 32 + ni * 16 + c;
                int h = n / 96, w = n - h * 96;
                int row0 = m0 + wm * 64 + mi * 16 + 4 * g;
                if (w < NOPE) {
                    #pragma unroll
                    for (int r = 0; r < 4; ++r)
                        kb[(size_t)(row0 + r) * DM + h * HD + w] = __float2bfloat16(acc[mi][ni][r]);
                } else {
                    int d = w - NOPE;
                    int b = row0 >> 10, s0 = row0 & (SEQ - 1);
                    ushort4 v4;
                    v4.x = bfbits(acc[mi][ni][0]);
                    v4.y = bfbits(acc[mi][ni][1]);
                    v4.z = bfbits(acc[mi][ni][2]);
                    v4.w = bfbits(acc[mi][ni][3]);
                    *(ushort4*)&vt_g[(((size_t)(b * NH + h) * HD + d) << 10) + s0] = v4;
                }
            }
    }
}

// ---------------------------------------------------------------------------
// k_attn: champion version (4 waves, 64 q rows, gload staging, LDS overlay).
// ---------------------------------------------------------------------------
__global__ __launch_bounds__(256) void k_attn(
    const bf16* __restrict__ qb, const bf16* __restrict__ kb,
    const bf16* __restrict__ vt_g, bf16* __restrict__ ab)
{
    __shared__ __align__(16) char stage[2][16384];

    const int orig = blockIdx.y * 8 + blockIdx.x;
    const int h  = (orig & 7) * 2 + ((orig >> 3) & 1);
    const int qt = orig >> 4;
    const int b = blockIdx.z;
    const int tid = threadIdx.x;
    const int lane = tid & 63, wave = tid >> 6;
    const int l31 = lane & 31, hi = lane >> 5;
    const int sp = wave >> 1, wq = wave & 1;
    const int q0 = qt * 64 + wq * 32;
    char* ks = stage[sp];
    char* vt = stage[sp] + 8192;

    const int scol = ((lane & 7) * 8) ^ ((lane >> 3) << 3);
    const int srowL = lane >> 3;

    bf16x8 qf[4];
    {
        const bf16* qrow = &qb[(size_t)(b * SEQ + q0 + l31) * DM + h * HD + 8 * hi];
        #pragma unroll
        for (int st = 0; st < 4; ++st)
            qf[st] = *(const bf16x8*)&qrow[16 * st];
    }

    f32x16 o0 = {}, o1 = {};
    float m_run = -3.0e38f, l_run = 0.f;
    const size_t vbase = ((size_t)(b * NH + h) * HD) << 10;

    for (int ktl = 0; ktl < 8; ++ktl) {
        const int kt = sp * 8 + ktl;
        __syncthreads();
        #pragma unroll
        for (int ps = 0; ps < 4; ++ps) {
            int rbase = ps * 16 + wq * 8;
            int row = rbase + srowL;
            gload16(&kb[(size_t)(b * SEQ + kt * 64 + row) * DM + h * HD + scol],
                    ks + rbase * 128);
            gload16(&vt_g[vbase + ((size_t)row << 10) + kt * 64 + scol],
                    vt + rbase * 128);
        }
        VMWAIT(0);
        __syncthreads();

        f32x16 sc0 = {}, sc1 = {};
        __builtin_amdgcn_s_setprio(1);
        #pragma unroll
        for (int st = 0; st < 4; ++st) {
            int colb = 32 * st + 16 * hi;
            int r0 = l31;
            bf16x8 kf0 = *(const bf16x8*)&ks[r0 * 128 + (colb ^ ((r0 & 7) << 4))];
            sc0 = __builtin_amdgcn_mfma_f32_32x32x16_bf16(kf0, qf[st], sc0, 0, 0, 0);
            int r1 = 32 + l31;
            bf16x8 kf1 = *(const bf16x8*)&ks[r1 * 128 + (colb ^ ((r1 & 7) << 4))];
            sc1 = __builtin_amdgcn_mfma_f32_32x32x16_bf16(kf1, qf[st], sc1, 0, 0, 0);
        }
        __builtin_amdgcn_s_setprio(0);

        float mt = fmaxf(sc0[0], sc1[0]);
        #pragma unroll
        for (int i = 1; i < 16; ++i) mt = fmaxf(mt, fmaxf(sc0[i], sc1[i]));
        mt = fmaxf(mt, __shfl_xor(mt, 32));

        if (!__all(mt <= m_run + 8.0f)) {
            float m_new = fmaxf(m_run, mt);
            float corr = exp2f(m_run - m_new);
            m_run = m_new;
            l_run *= corr;
            #pragma unroll
            for (int i = 0; i < 16; ++i) { o0[i] *= corr; o1[i] *= corr; }
        }
        float ls = 0.f;
        #pragma unroll
        for (int i = 0; i < 16; ++i) {
            sc0[i] = exp2f(sc0[i] - m_run);
            sc1[i] = exp2f(sc1[i] - m_run);
            ls += sc0[i] + sc1[i];
        }
        ls += __shfl_xor(ls, 32);
        l_run += ls;

        unsigned pk0[8], pk1[8];
        #pragma unroll
        for (int i = 0; i < 8; ++i) {
            pk0[i] = cvt_pk_bf16(sc0[2 * i], sc0[2 * i + 1]);
            pk1[i] = cvt_pk_bf16(sc1[2 * i], sc1[2 * i + 1]);
        }

        __builtin_amdgcn_s_setprio(1);
#define PV_SUB(PK, KK)                                                          \
        {                                                                       \
            _Pragma("unroll")                                                   \
            for (int s = 0; s < 2; ++s) {                                       \
                unsigned sx = hi ? PK[4*s]   : PK[4*s+2];                       \
                unsigned rx = __shfl_xor(sx, 32);                               \
                unsigned sy = hi ? PK[4*s+1] : PK[4*s+3];                       \
                unsigned ry = __shfl_xor(sy, 32);                               \
                int4 bi;                                                        \
                bi.x = hi ? (int)rx : (int)PK[4*s];                             \
                bi.y = hi ? (int)ry : (int)PK[4*s+1];                           \
                bi.z = hi ? (int)PK[4*s+2] : (int)rx;                           \
                bi.w = hi ? (int)PK[4*s+3] : (int)ry;                           \
                bf16x8 bfr = *(bf16x8*)&bi;                                     \
                int cb = (KK) * 64 + 32 * s + 16 * hi;                          \
                {                                                               \
                    int vr = l31;                                               \
                    bf16x8 vf = *(const bf16x8*)&vt[vr * 128 + (cb ^ ((vr & 7) << 4))]; \
                    o0 = __builtin_amdgcn_mfma_f32_32x32x16_bf16(vf, bfr, o0, 0, 0, 0); \
                }                                                               \
                {                                                               \
                    int vr = 32 + l31;                                          \
                    bf16x8 vf = *(const bf16x8*)&vt[vr * 128 + (cb ^ ((vr & 7) << 4))]; \
                    o1 = __builtin_amdgcn_mfma_f32_32x32x16_bf16(vf, bfr, o1, 0, 0, 0); \
                }                                                               \
            }                                                                   \
        }
        PV_SUB(pk0, 0)
        PV_SUB(pk1, 1)
#undef PV_SUB
        __builtin_amdgcn_s_setprio(0);
    }

    float* polB = (float*)stage[0];
    float* mllB = (float*)(stage[0] + 16640);

    __syncthreads();
    if (sp == 1) {
        #pragma unroll
        for (int i = 0; i < 16; ++i) {
            int d = (i & 3) + 8 * (i >> 2) + 4 * hi;
            polB[(wq * 32 + l31) * 65 + d]      = o0[i];
            polB[(wq * 32 + l31) * 65 + 32 + d] = o1[i];
        }
        if (hi == 0) {
            mllB[(wq * 32 + l31) * 2 + 0] = m_run;
            mllB[(wq * 32 + l31) * 2 + 1] = l_run;
        }
    }
    __syncthreads();
    if (sp == 0) {
        float m_b = mllB[(wq * 32 + l31) * 2 + 0];
        float l_b = mllB[(wq * 32 + l31) * 2 + 1];
        float M = fmaxf(m_run, m_b);
        float wa = exp2f(m_run - M), wb = exp2f(m_b - M);
        float inv = 1.0f / (l_run * wa + l_b * wb);
        #pragma unroll
        for (int i = 0; i < 16; ++i) {
            int d = (i & 3) + 8 * (i >> 2) + 4 * hi;
            o0[i] = (o0[i] * wa + polB[(wq * 32 + l31) * 65 + d]      * wb) * inv;
            o1[i] = (o1[i] * wa + polB[(wq * 32 + l31) * 65 + 32 + d] * wb) * inv;
        }
    }
    __syncthreads();
    if (sp == 0) {
        char* tb = stage[1] + (wq ? 8192 : 1024);
        #pragma unroll
        for (int i = 0; i < 8; ++i) {
            int dbase = 2 * (i & 1) + 8 * (i >> 1) + 4 * hi;
            *(unsigned*)&tb[l31 * 140 + (dbase) * 2]      = cvt_pk_bf16(o0[2 * i], o0[2 * i + 1]);
            *(unsigned*)&tb[l31 * 140 + (32 + dbase) * 2] = cvt_pk_bf16(o1[2 * i], o1[2 * i + 1]);
        }
        __builtin_amdgcn_s_waitcnt(0);
        #pragma unroll
        for (int p = 0; p < 8; ++p) {
            int idx = p * 64 + lane;
            int q = idx >> 4, c8 = idx & 15;
            int2 rv;
            rv.x = *(const int*)&tb[q * 140 + c8 * 8];
            rv.y = *(const int*)&tb[q * 140 + c8 * 8 + 4];
            *(int2*)&ab[(size_t)(b * SEQ + q0 + q) * DM + h * HD + c8 * 4] = rv;
        }
    }
}

// ---------------------------------------------------------------------------
// GEMM family: BK=32, 8 waves, gload16 staging, TRIPLE-buffered LDS ->
// one barrier per K-step. XCD-swizzled block mapping. (champion version)
// ---------------------------------------------------------------------------
__global__ __launch_bounds__(512) void k_mm_plain(
    const bf16* __restrict__ A, const bf16* __restrict__ Bt, bf16* __restrict__ C)
{
    __shared__ __align__(16) char As[3][8192];
    __shared__ __align__(16) char Bs[3][4096];
    const int tid = threadIdx.x;
    const int lane = tid & 63, wave = tid >> 6;
    const int g = lane >> 4, c = lane & 15;
    const int wm = wave >> 1, wn = wave & 1;
    int orig = blockIdx.y * 16 + blockIdx.x;
    int swz = (orig & 7) * 32 + (orig >> 3);
    const int n0 = (swz & 15) * 64, m0 = (swz >> 4) * 128;

    const int ldr = lane >> 2;
    const int ldc = (lane & 3) * 8;
    const bf16* agp = &A[(size_t)(m0 + wave * 16 + ldr) * DM + ldc];
    const bool doB = wave >= 4;
    const bf16* bgp = &Bt[(size_t)(n0 + (wave & 3) * 16 + ldr) * DM + ldc];
    const int aoffL = wave * 1024, boffL = (wave & 3) * 1024;

    f32x4 acc[2][2] = {};
    const int NT = DM / 32;
    gload16(agp, As[0] + aoffL);
    if (doB) gload16(bgp, Bs[0] + boffL);
    int cur = 0;
    for (int k = 0; k < NT; ++k) {
        if (k + 1 < NT) {
            int nxt = (cur + 1) % 3;
            gload16(agp + (k + 1) * 32, As[nxt] + aoffL);
            if (doB) gload16(bgp + (k + 1) * 32, Bs[nxt] + boffL);
            if (doB) VMWAIT(2); else VMWAIT(1);
        } else {
            VMWAIT(0);
        }
        barrier_();
        bf16x8 af[2], bfx[2];
        #pragma unroll
        for (int mi = 0; mi < 2; ++mi)
            af[mi] = *(const bf16x8*)&As[cur][(wm * 32 + mi * 16 + c) * 64 + g * 16];
        #pragma unroll
        for (int ni = 0; ni < 2; ++ni)
            bfx[ni] = *(const bf16x8*)&Bs[cur][(wn * 32 + ni * 16 + c) * 64 + g * 16];
        #pragma unroll
        for (int mi = 0; mi < 2; ++mi)
            #pragma unroll
            for (int ni = 0; ni < 2; ++ni)
                acc[mi][ni] = __builtin_amdgcn_mfma_f32_16x16x32_bf16(af[mi], bfx[ni], acc[mi][ni], 0, 0, 0);
        cur = (cur + 1) % 3;
    }
    #pragma unroll
    for (int mi = 0; mi < 2; ++mi)
        #pragma unroll
        for (int ni = 0; ni < 2; ++ni)
            #pragma unroll
            for (int r = 0; r < 4; ++r)
                C[(size_t)(m0 + wm * 32 + mi * 16 + 4 * g + r) * DM + n0 + wn * 32 + ni * 16 + c]
                    = __float2bfloat16(acc[mi][ni][r]);
}

// merged routed (z=0..3) + shared (z=4) gate+up, triple-buffered
__global__ __launch_bounds__(512) void k_mm_gu_all(
    const bf16* __restrict__ X, const bf16* __restrict__ egT,
    const bf16* __restrict__ euT, const bf16* __restrict__ sgT,
    const bf16* __restrict__ suT, const int* __restrict__ cnt,
    const int* __restrict__ lists, bf16* __restrict__ act_r,
    bf16* __restrict__ act_s)
{
    const int e = blockIdx.z;
    const bool SH = (e == 4);
    const int ntok = SH ? T : cnt[e];
    int orig = blockIdx.y * 16 + blockIdx.x;
    int swz = (orig & 7) * 32 + (orig >> 3);
    const int n0 = (swz & 15) * 64, m0 = (swz >> 4) * 128;
    if (m0 >= ntok) return;
    __shared__ __align__(16) char As[3][8192];
    __shared__ __align__(16) char Bg[3][4096];
    __shared__ __align__(16) char Bu[3][4096];
    __shared__ int rowid[128];
    const int tid = threadIdx.x;
    if (tid < 128) {
        int idx = m0 + tid;
        rowid[tid] = SH ? idx : lists[e * T + (idx < ntok ? idx : ntok - 1)];
    }
    __syncthreads();
    const int lane = tid & 63, wave = tid >> 6;
    const int g = lane >> 4, c = lane & 15;
    const int wm = wave >> 1, wn = wave & 1;
    const bf16* Bge = SH ? sgT : egT + (size_t)e * HID * DM;
    const bf16* Bue = SH ? suT : euT + (size_t)e * HID * DM;
    bf16* act = SH ? act_s : act_r;

    const int ldr = lane >> 2;
    const int ldc = (lane & 3) * 8;
    const int myTok = rowid[wave * 16 + ldr];
    const bf16* agp = &X[(size_t)myTok * DM + ldc];
    const bool isG = wave < 4;
    const bf16* bgp = (isG ? Bge : Bue) + (size_t)(n0 + (wave & 3) * 16 + ldr) * DM + ldc;
    const int aoffL = wave * 1024, boffL = (wave & 3) * 1024;

    f32x4 accg[2][2] = {}, accu[2][2] = {};
    const int NT = DM / 32;
    gload16(agp, As[0] + aoffL);
    gload16(bgp, (isG ? Bg[0] : Bu[0]) + boffL);
    int cur = 0;
    for (int k = 0; k < NT; ++k) {
        if (k + 1 < NT) {
            int nxt = (cur + 1) % 3;
            gload16(agp + (k + 1) * 32, As[nxt] + aoffL);
            gload16(bgp + (k + 1) * 32, (isG ? Bg[nxt] : Bu[nxt]) + boffL);
            VMWAIT(2);
        } else {
            VMWAIT(0);
        }
        barrier_();
        bf16x8 af[2], gf[2], uf[2];
        #pragma unroll
        for (int mi = 0; mi < 2; ++mi)
            af[mi] = *(const bf16x8*)&As[cur][(wm * 32 + mi * 16 + c) * 64 + g * 16];
        #pragma unroll
        for (int ni = 0; ni < 2; ++ni) {
            gf[ni] = *(const bf16x8*)&Bg[cur][(wn * 32 + ni * 16 + c) * 64 + g * 16];
            uf[ni] = *(const bf16x8*)&Bu[cur][(wn * 32 + ni * 16 + c) * 64 + g * 16];
        }
        #pragma unroll
        for (int mi = 0; mi < 2; ++mi)
            #pragma unroll
            for (int ni = 0; ni < 2; ++ni) {
                accg[mi][ni] = __builtin_amdgcn_mfma_f32_16x16x32_bf16(af[mi], gf[ni], accg[mi][ni], 0, 0, 0);
                accu[mi][ni] = __builtin_amdgcn_mfma_f32_16x16x32_bf16(af[mi], uf[ni], accu[mi][ni], 0, 0, 0);
            }
        cur = (cur + 1) % 3;
    }
    #pragma unroll
    for (int mi = 0; mi < 2; ++mi)
        #pragma unroll
        for (int ni = 0; ni < 2; ++ni)
            #pragma unroll
            for (int r = 0; r < 4; ++r) {
                int lr = wm * 32 + mi * 16 + 4 * g + r;
                if (!SH && m0 + lr >= ntok) continue;
                int token = rowid[lr];
                float gv = accg[mi][ni][r], uv = accu[mi][ni][r];
                act[(size_t)token * HID + n0 + wn * 32 + ni * 16 + c] =
                    __float2bfloat16(gv * sigmoidf_(gv) * uv);
            }
}

// fused down: out = (act_r @ exp_down[e]) * wtok + (act_s @ sh_down), tri-buffered
__global__ __launch_bounds__(512) void k_mm_down_f(
    const bf16* __restrict__ Xr, const bf16* __restrict__ Xs,
    const bf16* __restrict__ edT, const bf16* __restrict__ sdT,
    const int* __restrict__ cnt, const int* __restrict__ lists,
    const float* __restrict__ wtok, float* __restrict__ out)
{
    const int e = blockIdx.z;
    const int ntok = cnt[e];
    int orig = blockIdx.y * 16 + blockIdx.x;
    int swz = (orig & 7) * 32 + (orig >> 3);
    const int n0 = (swz & 15) * 64, m0 = (swz >> 4) * 128;
    if (m0 >= ntok) return;
    __shared__ __align__(16) char Ar[3][8192];
    __shared__ __align__(16) char Az[3][8192];
    __shared__ __align__(16) char Br[3][4096];
    __shared__ __align__(16) char Bz[3][4096];
    __shared__ int rowid[128];
    const int tid = threadIdx.x;
    if (tid < 128) {
        int idx = m0 + tid;
        rowid[tid] = lists[e * T + (idx < ntok ? idx : ntok - 1)];
    }
    __syncthreads();
    const int lane = tid & 63, wave = tid >> 6;
    const int g = lane >> 4, c = lane & 15;
    const int wm = wave >> 1, wn = wave & 1;
    const bf16* Bde = edT + (size_t)e * HID * DM;

    const int ldr = lane >> 2;
    const int ldc = (lane & 3) * 8;
    const int myTok = rowid[wave * 16 + ldr];
    const bf16* agr = &Xr[(size_t)myTok * HID + ldc];
    const bf16* ags = &Xs[(size_t)myTok * HID + ldc];
    const bool isR = wave < 4;
    const bf16* bgp = (isR ? Bde : sdT) + (size_t)(n0 + (wave & 3) * 16 + ldr) * HID + ldc;
    const int aoffL = wave * 1024, boffL = (wave & 3) * 1024;

    f32x4 accr[2][2] = {}, accs[2][2] = {};
    const int NT = HID / 32;
    gload16(agr, Ar[0] + aoffL);
    gload16(ags, Az[0] + aoffL);
    gload16(bgp, (isR ? Br[0] : Bz[0]) + boffL);
    int cur = 0;
    for (int k = 0; k < NT; ++k) {
        if (k + 1 < NT) {
            int nxt = (cur + 1) % 3;
            gload16(agr + (k + 1) * 32, Ar[nxt] + aoffL);
            gload16(ags + (k + 1) * 32, Az[nxt] + aoffL);
            gload16(bgp + (k + 1) * 32, (isR ? Br[nxt] : Bz[nxt]) + boffL);
            VMWAIT(3);
        } else {
            VMWAIT(0);
        }
        barrier_();
        bf16x8 afr[2], afs[2], bfr[2], bfs[2];
        #pragma unroll
        for (int mi = 0; mi < 2; ++mi) {
            afr[mi] = *(const bf16x8*)&Ar[cur][(wm * 32 + mi * 16 + c) * 64 + g * 16];
            afs[mi] = *(const bf16x8*)&Az[cur][(wm * 32 + mi * 16 + c) * 64 + g * 16];
        }
        #pragma unroll
        for (int ni = 0; ni < 2; ++ni) {
            bfr[ni] = *(const bf16x8*)&Br[cur][(wn * 32 + ni * 16 + c) * 64 + g * 16];
            bfs[ni] = *(const bf16x8*)&Bz[cur][(wn * 32 + ni * 16 + c) * 64 + g * 16];
        }
        #pragma unroll
        for (int mi = 0; mi < 2; ++mi)
            #pragma unroll
            for (int ni = 0; ni < 2; ++ni) {
                accr[mi][ni] = __builtin_amdgcn_mfma_f32_16x16x32_bf16(afr[mi], bfr[ni], accr[mi][ni], 0, 0, 0);
                accs[mi][ni] = __builtin_amdgcn_mfma_f32_16x16x32_bf16(afs[mi], bfs[ni], accs[mi][ni], 0, 0, 0);
            }
        cur = (cur + 1) % 3;
    }
    #pragma unroll
    for (int mi = 0; mi < 2; ++mi)
        #pragma unroll
        for (int ni = 0; ni < 2; ++ni)
            #pragma unroll
            for (int r = 0; r < 4; ++r) {
                int lr = wm * 32 + mi * 16 + 4 * g + r;
                if (m0 + lr >= ntok) continue;
                int token = rowid[lr];
                int bt = token >> 10, st = token & (SEQ - 1);
                size_t oo = (size_t)st * (BATCH * DM) + bt * DM + n0 + wn * 32 + ni * 16 + c;
                out[oo] = accr[mi][ni][r] * wtok[token] + accs[mi][ni][r];
            }
}

// ---------------------------------------------------------------------------
__global__ __launch_bounds__(256) void k_gate(
    const bf16* __restrict__ y, const float* __restrict__ gw,
    int* __restrict__ cnt, int* __restrict__ lists, float* __restrict__ wtok)
{
    int warp = threadIdx.x >> 6, lane = threadIdx.x & 63;
    int t = blockIdx.x * 4 + warp;
    float acc[NEXP] = {};
    for (int d = lane; d < DM; d += 64) {
        float xv = __bfloat162float(y[(size_t)t * DM + d]);
        #pragma unroll
        for (int e = 0; e < NEXP; ++e) acc[e] += xv * gw[e * DM + d];
    }
    #pragma unroll
    for (int off = 32; off; off >>= 1)
        #pragma unroll
        for (int e = 0; e < NEXP; ++e) acc[e] += __shfl_xor(acc[e], off);
    if (lane == 0) {
        float mx = fmaxf(fmaxf(acc[0], acc[1]), fmaxf(acc[2], acc[3]));
        float ex[NEXP], ssum = 0.f;
        #pragma unroll
        for (int e = 0; e < NEXP; ++e) { ex[e] = __expf(acc[e] - mx); ssum += ex[e]; }
        int best = 0; float bv = ex[0];
        #pragma unroll
        for (int e = 1; e < NEXP; ++e) if (ex[e] > bv) { bv = ex[e]; best = e; }
        wtok[t] = bv / ssum;
        int pos = atomicAdd(&cnt[best], 1);
        lists[best * T + pos] = t;
    }
}

// ---------------------------------------------------------------------------
extern "C" void kernel_launch(void* const* d_in, const int* in_sizes, int n_in,
                              void* d_out, int out_size, void* d_ws, size_t ws_size,
                              hipStream_t stream) {
    (void)in_sizes; (void)n_in; (void)out_size; (void)ws_size;
    const float* dec      = (const float*)d_in[0];
    const float* wq_a     = (const float*)d_in[1];
    const float* q_norm_w = (const float*)d_in[2];
    const float* wq_b     = (const float*)d_in[3];
    const float* wkv_a    = (const float*)d_in[4];
    const float* kv_norm_w= (const float*)d_in[5];
    const float* wkv_b    = (const float*)d_in[6];
    const float* wo       = (const float*)d_in[7];
    const float* gate_w   = (const float*)d_in[8];
    const float* exp_gate = (const float*)d_in[9];
    const float* exp_up   = (const float*)d_in[10];
    const float* exp_down = (const float*)d_in[11];
    const float* sh_gate  = (const float*)d_in[12];
    const float* sh_up    = (const float*)d_in[13];
    const float* sh_down  = (const float*)d_in[14];
    float* out = (float*)d_out;

    char* W = (char*)d_ws;
    bf16* qb   = (bf16*)(W);                    // 4MB; reused as y
    bf16* kb   = (bf16*)(W + (4ull  << 20));    // 4MB; reused as act_r
    bf16* vt_g = (bf16*)(W + (8ull  << 20));    // 4MB; reused as act_s
    char* SMALL = W + (12ull << 20);
    bf16* ab   = (bf16*)(W + (12ull << 20));    // 4MB (aliases SMALL, dead by then)
    bf16* woT = (bf16*)(W + (16ull << 20));
    bf16* sgT = (bf16*)(W + (18ull << 20));
    bf16* suT = (bf16*)(W + (20ull << 20));
    bf16* sdT = (bf16*)(W + (22ull << 20));
    bf16* egT = (bf16*)(W + (24ull << 20));
    bf16* euT = (bf16*)(W + (32ull << 20));
    bf16* edT = (bf16*)(W + (40ull << 20));
    int*   cnt   = (int*)(W + (48ull << 20));
    int*   lists = cnt + 16;
    float* wtok  = (float*)(lists + NEXP * T);
    bf16* yb    = qb;
    bf16* act_r = kb;
    bf16* act_s = vt_g;

    float* lora4 = (float*)(SMALL);
    bf16*  loraT = (bf16*) (SMALL + 1179648);
    bf16*  wqbT  = (bf16*) (SMALL + 1343488);
    bf16*  wkvbT = (bf16*) (SMALL + 1409024);
    bf16*  nrmq  = (bf16*) (SMALL + 1507328);
    bf16*  nrmkv = (bf16*) (SMALL + 1638400);
    float* ctab  = (float*)(SMALL + 1769472);
    float* stab  = (float*)(SMALL + 2818048);

    k_setup<<<dim3(32, 32, 20), 256, 0, stream>>>(
        wo, sh_gate, sh_up, sh_down, exp_gate, exp_up, exp_down,
        woT, sgT, suT, sdT, egT, euT, edT,
        wq_a, wkv_a, wq_b, wkv_b, loraT, wqbT, wkvbT, ctab, stab);

    k_p1<<<dim3(2, 16), 256, 0, stream>>>(dec, loraT, lora4);
    k_p2m<<<T, 256, 0, stream>>>(lora4, q_norm_w, kv_norm_w, ctab, stab,
                                 nrmq, nrmkv, kb, cnt);
    k_p3<<<dim3(24, 16, 2), 256, 0, stream>>>(nrmq, wqbT, nrmkv, wkvbT,
                                              ctab, stab, qb, kb, vt_g);

    k_attn<<<dim3(8, 32, BATCH), 256, 0, stream>>>(qb, kb, vt_g, ab);
    k_mm_plain<<<dim3(16, 16), 512, 0, stream>>>(ab, woT, yb);
    k_gate<<<T / 4, 256, 0, stream>>>(yb, gate_w, cnt, lists, wtok);
    k_mm_gu_all<<<dim3(16, 16, NEXP + 1), 512, 0, stream>>>(
        yb, egT, euT, sgT, suT, cnt, lists, act_r, act_s);
    k_mm_down_f<<<dim3(16, 16, NEXP), 512, 0, stream>>>(
        act_r, act_s, edT, sdT, cnt, lists, wtok, out);
}